// Round 5
// baseline (1249.789 us; speedup 1.0000x reference)
//
#include <hip/hip_runtime.h>
#include <hip/hip_bf16.h>
#include <cstdint>
#include <cstddef>

typedef float    f32x4  __attribute__((ext_vector_type(4)));
typedef __bf16   bf16x8 __attribute__((ext_vector_type(8)));
typedef _Float16 f16x4  __attribute__((ext_vector_type(4)));
typedef _Float16 f16x8  __attribute__((ext_vector_type(8)));

__device__ __forceinline__ unsigned short f2bf(float x){
  unsigned u = __float_as_uint(x);
  return (unsigned short)((u + 0x7fffu + ((u >> 16) & 1u)) >> 16);
}
__device__ __forceinline__ float bfhi(unsigned short h){
  return __uint_as_float(((unsigned)h) << 16);
}

// ---------------- graph structure ----------------
// XCD-filtered histogram: block b handles chunk b>>3, keeps dst with range-id == b&7.
__global__ void k_deg_hist(const int* __restrict__ dst, int* __restrict__ deg, int E,
                           unsigned long long M){
  int f   = blockIdx.x & 7;
  int cid = blockIdx.x >> 3;
  int nch = gridDim.x >> 3;
  for(int i = cid*blockDim.x + threadIdx.x; i < E; i += nch*blockDim.x){
    int d = dst[i];
    int xf = (int)(((unsigned long long)(unsigned)d * M) >> 40);
    if(xf == f) atomicAdd(&deg[d], 1);
  }
}

__global__ void k_batch_hist(const int* __restrict__ batch, int* __restrict__ cnt, int n){
  __shared__ int h[64];
  if(threadIdx.x<64) h[threadIdx.x]=0;
  __syncthreads();
  int i = blockIdx.x*blockDim.x + threadIdx.x;
  int stride = gridDim.x*blockDim.x;
  for(; i<n; i+=stride) atomicAdd(&h[batch[i]], 1);
  __syncthreads();
  if(threadIdx.x<64 && h[threadIdx.x]) atomicAdd(&cnt[threadIdx.x], h[threadIdx.x]);
}

__global__ void k_dinv(const int* __restrict__ deg, float* __restrict__ dinv, int n){
  int i = blockIdx.x*blockDim.x + threadIdx.x;
  if(i<n) dinv[i] = rsqrtf((float)(deg[i]+1));   // +1 = self loop
}

__global__ void k_scan1(const int* __restrict__ deg, int* __restrict__ bsum, int n){
  __shared__ int s[256];
  int base = blockIdx.x*1024 + threadIdx.x*4;
  int acc=0;
  #pragma unroll
  for(int j=0;j<4;j++){ int i=base+j; if(i<n) acc+=deg[i]; }
  s[threadIdx.x]=acc; __syncthreads();
  for(int off=128;off>0;off>>=1){
    if(threadIdx.x<off) s[threadIdx.x]+=s[threadIdx.x+off];
    __syncthreads();
  }
  if(threadIdx.x==0) bsum[blockIdx.x]=s[0];
}

__global__ void k_scan2(int* __restrict__ bsum, int nblk, int* __restrict__ rowptr, int n){
  __shared__ int s[128];
  int t=threadIdx.x;
  int v = (t<nblk)? bsum[t] : 0;
  s[t]=v; __syncthreads();
  for(int off=1; off<128; off<<=1){
    int a = (t>=off)? s[t-off] : 0;
    __syncthreads();
    s[t]+=a;
    __syncthreads();
  }
  if(t<nblk) bsum[t]=s[t]-v;         // exclusive block offsets
  if(t==127) rowptr[n]=s[127];       // total = E
}

__global__ void k_scan3(const int* __restrict__ deg, const int* __restrict__ bsum,
                        int* __restrict__ rowptr, int* __restrict__ cursor, int n){
  __shared__ int s[256];
  int base = blockIdx.x*1024 + threadIdx.x*4;
  int v[4]; int acc=0;
  #pragma unroll
  for(int j=0;j<4;j++){ int i=base+j; v[j]=(i<n)?deg[i]:0; acc+=v[j]; }
  s[threadIdx.x]=acc; __syncthreads();
  for(int off=1; off<256; off<<=1){
    int a = (threadIdx.x>=off)? s[threadIdx.x-off] : 0;
    __syncthreads();
    s[threadIdx.x]+=a;
    __syncthreads();
  }
  int excl = s[threadIdx.x]-acc + bsum[blockIdx.x];
  #pragma unroll
  for(int j=0;j<4;j++){
    int i=base+j;
    if(i<n){ rowptr[i]=excl; cursor[i]=excl; excl+=v[j]; }
  }
}

// XCD-filtered CSR fill
__global__ void k_csr_fill(const int* __restrict__ src, const int* __restrict__ dst,
                           int* __restrict__ cursor, int* __restrict__ adj, int E,
                           unsigned long long M){
  int f   = blockIdx.x & 7;
  int cid = blockIdx.x >> 3;
  int nch = gridDim.x >> 3;
  for(int i = cid*blockDim.x + threadIdx.x; i < E; i += nch*blockDim.x){
    int d = dst[i];
    int xf = (int)(((unsigned long long)(unsigned)d * M) >> 40);
    if(xf == f){
      int p = atomicAdd(&cursor[d], 1);
      adj[p] = src[i];
    }
  }
}

// ---------------- W preprocess: transpose + bf16 hi/lo split ----------------

__global__ void k_prep_w(const float* __restrict__ W, unsigned short* __restrict__ Wh,
                         unsigned short* __restrict__ Wl, int K, int F){
  int i = blockIdx.x*256 + threadIdx.x;
  if(i < K*F){
    int k = i / F, f = i % F;
    float a = W[i];
    unsigned short h = f2bf(a);
    Wh[(size_t)f*K + k] = h;
    Wl[(size_t)f*K + k] = f2bf(a - bfhi(h));
  }
}

// x16[node,f] = x[node,f] * dinv[node]  (fp16)
__global__ void k_prep_x(const float* __restrict__ x, const float* __restrict__ dinv,
                         _Float16* __restrict__ x16, int n){
  int tid = blockIdx.x*256 + threadIdx.x;
  int node = tid >> 5;
  if(node>=n) return;
  int c4 = tid & 31;
  size_t idx = ((size_t)node<<5) + c4;
  float4 v = ((const float4*)x)[idx];
  float d = dinv[node];
  f16x4 o;
  o[0]=(_Float16)(v.x*d); o[1]=(_Float16)(v.y*d); o[2]=(_Float16)(v.z*d); o[3]=(_Float16)(v.w*d);
  ((f16x4*)x16)[idx] = o;
}

// ---------------- aggregate (fp16 gather, fp32 accum, fp16 out) ----------------
// out[i] = dinv[i] * ( sum_{e:dst=i} z[src] + z[i] ) + bias;  F = 8<<lg8 feats
__global__ void k_agg16(const _Float16* __restrict__ zs, const int* __restrict__ rowptr,
                        const int* __restrict__ adj, const float* __restrict__ dinv,
                        const float* __restrict__ bias, _Float16* __restrict__ out,
                        int n, int lg8){
  int tid = blockIdx.x*blockDim.x + threadIdx.x;
  int node = tid >> lg8;
  if(node>=n) return;
  int c8 = tid & ((1<<lg8)-1);
  const f16x8* z8 = (const f16x8*)zs;
  size_t rb = ((size_t)node<<lg8) + c8;
  f16x8 self = z8[rb];
  float a0[8], a1[8];
  #pragma unroll
  for(int j=0;j<8;j++){ a0[j] = (float)self[j]; a1[j]=0.f; }
  int e = rowptr[node], end = rowptr[node+1];
  for(; e+1<end; e+=2){
    int s0=adj[e], s1=adj[e+1];
    f16x8 v0 = z8[((size_t)s0<<lg8)+c8];
    f16x8 v1 = z8[((size_t)s1<<lg8)+c8];
    #pragma unroll
    for(int j=0;j<8;j++){ a0[j]+=(float)v0[j]; a1[j]+=(float)v1[j]; }
  }
  if(e<end){
    f16x8 v0 = z8[((size_t)adj[e]<<lg8)+c8];
    #pragma unroll
    for(int j=0;j<8;j++) a0[j]+=(float)v0[j];
  }
  float di = dinv[node];
  f16x8 o;
  #pragma unroll
  for(int j=0;j<8;j++){
    float r = (a0[j]+a1[j])*di;
    if(bias) r += bias[(c8<<3)+j];
    o[j] = (_Float16)r;
  }
  ((f16x8*)out)[rb] = o;
}

// ---------------- MFMA GEMM with bf16 hi/lo split ----------------

template<typename AT> struct AFrag;
template<> struct AFrag<float>{
  float4 a,b;
  __device__ __forceinline__ void load(const float* p){ a=*(const float4*)p; b=*(const float4*)(p+4); }
  __device__ __forceinline__ void get(float o[8]) const {
    o[0]=a.x;o[1]=a.y;o[2]=a.z;o[3]=a.w;o[4]=b.x;o[5]=b.y;o[6]=b.z;o[7]=b.w;
  }
};
template<> struct AFrag<_Float16>{
  f16x8 v;
  __device__ __forceinline__ void load(const _Float16* p){ v=*(const f16x8*)p; }
  __device__ __forceinline__ void get(float o[8]) const {
    #pragma unroll
    for(int j=0;j<8;j++) o[j]=(float)v[j];
  }
};

// C[n,F] = act(A[n,K]) @ W[K,F]; act = BN? relu(A*sc+sh) : A
// W pre-transposed/split: Bh/Bl = bf16 [F][K]. Epilogue: +bias (BIAS), *rsc[row] (RSC).
template<int K, int F, bool BN, bool BIAS, bool RSC, typename AT, typename OT>
__global__ __launch_bounds__(256,2) void k_gemm_mfma(const AT* __restrict__ A,
    const unsigned short* __restrict__ Bh, const unsigned short* __restrict__ Bl,
    const float* __restrict__ sc, const float* __restrict__ sh,
    const float* __restrict__ bias, const float* __restrict__ rsc,
    OT* __restrict__ C, int n){
  constexpr int NF = F/16;
  const int l   = threadIdx.x & 63;
  const int w   = threadIdx.x >> 6;
  const int rlo = l & 15;            // A row within frag / C col within frag
  const int khi = l >> 4;            // k-group (0..3)
  const int row0 = blockIdx.x*128 + w*32;

  f32x4 acc[2][NF];
  #pragma unroll
  for(int i=0;i<2;i++)
    #pragma unroll
    for(int j=0;j<NF;j++) acc[i][j] = (f32x4){0.f,0.f,0.f,0.f};

  const size_t e0 = (size_t)min(row0 + rlo,      n-1) * K + khi*8;
  const size_t e1 = (size_t)min(row0 + 16 + rlo, n-1) * K + khi*8;

  AFrag<AT> c0,c1,x0f,x1f;
  c0.load(A + e0); c1.load(A + e1);

  #pragma unroll 1
  for(int k0=0; k0<K; k0+=32){
    if(k0+32 < K){
      x0f.load(A + e0 + k0 + 32);
      x1f.load(A + e1 + k0 + 32);
    }
    float scr[8], shr[8];
    if(BN){
      float4 s0 = *(const float4*)(sc + k0 + khi*8);
      float4 s1 = *(const float4*)(sc + k0 + khi*8 + 4);
      float4 t0 = *(const float4*)(sh + k0 + khi*8);
      float4 t1 = *(const float4*)(sh + k0 + khi*8 + 4);
      scr[0]=s0.x;scr[1]=s0.y;scr[2]=s0.z;scr[3]=s0.w;scr[4]=s1.x;scr[5]=s1.y;scr[6]=s1.z;scr[7]=s1.w;
      shr[0]=t0.x;shr[1]=t0.y;shr[2]=t0.z;shr[3]=t0.w;shr[4]=t1.x;shr[5]=t1.y;shr[6]=t1.z;shr[7]=t1.w;
    }
    union { unsigned short u[8]; bf16x8 v; } H0,L0,H1,L1;
    {
      float v0[8], v1[8];
      c0.get(v0); c1.get(v1);
      #pragma unroll
      for(int j=0;j<8;j++){
        float y0 = v0[j], y1 = v1[j];
        if(BN){ y0 = fmaxf(fmaf(y0,scr[j],shr[j]),0.f); y1 = fmaxf(fmaf(y1,scr[j],shr[j]),0.f); }
        unsigned short h0 = f2bf(y0), h1 = f2bf(y1);
        H0.u[j]=h0; L0.u[j]=f2bf(y0 - bfhi(h0));
        H1.u[j]=h1; L1.u[j]=f2bf(y1 - bfhi(h1));
      }
    }
    bf16x8 ah0=H0.v, al0=L0.v, ah1=H1.v, al1=L1.v;
    #pragma unroll
    for(int cf=0; cf<NF; cf++){
      size_t boff = (size_t)(cf*16 + rlo)*K + k0 + khi*8;
      bf16x8 bh = *(const bf16x8*)(Bh + boff);
      bf16x8 bl = *(const bf16x8*)(Bl + boff);
      acc[0][cf] = __builtin_amdgcn_mfma_f32_16x16x32_bf16(ah0, bh, acc[0][cf], 0,0,0);
      acc[1][cf] = __builtin_amdgcn_mfma_f32_16x16x32_bf16(ah1, bh, acc[1][cf], 0,0,0);
      acc[0][cf] = __builtin_amdgcn_mfma_f32_16x16x32_bf16(al0, bh, acc[0][cf], 0,0,0);
      acc[1][cf] = __builtin_amdgcn_mfma_f32_16x16x32_bf16(al1, bh, acc[1][cf], 0,0,0);
      acc[0][cf] = __builtin_amdgcn_mfma_f32_16x16x32_bf16(ah0, bl, acc[0][cf], 0,0,0);
      acc[1][cf] = __builtin_amdgcn_mfma_f32_16x16x32_bf16(ah1, bl, acc[1][cf], 0,0,0);
    }
    c0=x0f; c1=x1f;
  }

  // epilogue: C/D layout col=lane&15 (+16cf), row=(lane>>4)*4+reg (+16rf)
  #pragma unroll
  for(int rf=0; rf<2; rf++){
    #pragma unroll
    for(int r=0; r<4; r++){
      int m = row0 + rf*16 + khi*4 + r;
      if(m < n){
        float rs = RSC ? rsc[m] : 1.f;
        #pragma unroll
        for(int cf=0; cf<NF; cf++){
          int col = rlo + 16*cf;
          float v = acc[rf][cf][r];
          if(BIAS) v += bias[col];
          v *= rs;
          C[(size_t)m*F + col] = (OT)v;
        }
      }
    }
  }
}

// ---------------- BatchNorm stats (fp16 input, vectorized, LDS-reduced) ----------------

__global__ __launch_bounds__(256) void k_bn_stats16(const _Float16* __restrict__ h,
                            float* __restrict__ sums, float* __restrict__ sumsq,
                            int n, int lgF){
  const int C8  = 1 << (lgF-3);            // f16x8 chunks per row
  const int c8  = threadIdx.x & (C8-1);
  const int sub = threadIdx.x >> (lgF-3);
  const int rpb = 256 >> (lgF-3);          // rows per pass per block
  float s[8], s2[8];
  #pragma unroll
  for(int j=0;j<8;j++){ s[j]=0.f; s2[j]=0.f; }
  for(int row = blockIdx.x*rpb + sub; row < n; row += gridDim.x*rpb){
    f16x8 v = ((const f16x8*)h)[(size_t)row*C8 + c8];
    #pragma unroll
    for(int j=0;j<8;j++){ float f=(float)v[j]; s[j]+=f; s2[j]=fmaf(f,f,s2[j]); }
  }
  __shared__ float rs [256*9];
  __shared__ float rs2[256*9];
  #pragma unroll
  for(int j=0;j<8;j++){ rs[threadIdx.x*9+j]=s[j]; rs2[threadIdx.x*9+j]=s2[j]; }
  __syncthreads();
  for(int half = rpb>>1; half>=1; half>>=1){
    if(sub < half){
      int o = (threadIdx.x + half*C8)*9;
      #pragma unroll
      for(int j=0;j<8;j++){ rs[threadIdx.x*9+j]+=rs[o+j]; rs2[threadIdx.x*9+j]+=rs2[o+j]; }
    }
    __syncthreads();
  }
  if(sub==0){
    #pragma unroll
    for(int j=0;j<8;j++){
      atomicAdd(&sums [c8*8+j], rs [threadIdx.x*9+j]);
      atomicAdd(&sumsq[c8*8+j], rs2[threadIdx.x*9+j]);
    }
  }
}

__global__ void k_bn_finalize(const float* __restrict__ sums, const float* __restrict__ sumsq,
                              const float* __restrict__ g, const float* __restrict__ be,
                              float* __restrict__ scale, float* __restrict__ shift, int n, int F){
  int f = threadIdx.x;
  if(f<F){
    float mu = sums[f]/(float)n;
    float var = sumsq[f]/(float)n - mu*mu;
    float sc = g[f]*rsqrtf(var+1e-5f);
    scale[f] = sc;
    shift[f] = fmaf(-mu, sc, be[f]);
  }
}

// ---------------- head: (BN2+relu) + LN + attention + pool + MLP ----------------

__global__ void k_ln_att(const _Float16* __restrict__ x, const float* __restrict__ bsc, const float* __restrict__ bsh,
                         const float* __restrict__ g, const float* __restrict__ b,
                         const float* __restrict__ att, float* __restrict__ lnx, float* __restrict__ wv,
                         float* __restrict__ Ssum, int n){
  int lane = threadIdx.x & 63;
  int wid = (blockIdx.x<<2) + (threadIdx.x>>6);
  float gl=g[lane], bl=b[lane], al=att[lane];
  float scl=bsc[lane], shl=bsh[lane];
  float wacc=0.f;
  for(int node=wid; node<n; node+=4096){
    float raw = (float)x[((size_t)node<<6)+lane];
    float v = fmaxf(fmaf(raw, scl, shl), 0.f);     // fused BN2 + relu
    float s=v;
    #pragma unroll
    for(int o=32;o>0;o>>=1) s += __shfl_xor(s,o);
    float mu = s*0.015625f;
    float d = v-mu;
    float q = d*d;
    #pragma unroll
    for(int o=32;o>0;o>>=1) q += __shfl_xor(q,o);
    float ln = d*rsqrtf(q*0.015625f + 1e-5f)*gl + bl;
    lnx[((size_t)node<<6)+lane] = ln;
    float a = ln*al;
    #pragma unroll
    for(int o=32;o>0;o>>=1) a += __shfl_xor(a,o);
    float wgt = expf(tanhf(a));
    if(lane==0) wv[node]=wgt;
    wacc += wgt;
  }
  __shared__ float sred[4];
  if(lane==0) sred[threadIdx.x>>6]=wacc;
  __syncthreads();
  if(threadIdx.x==0) atomicAdd(Ssum, sred[0]+sred[1]+sred[2]+sred[3]);
}

__global__ void k_pool(const float* __restrict__ lnx, const float* __restrict__ wv,
                       const int* __restrict__ batch, float* __restrict__ psum, int n){
  int lane = threadIdx.x & 63;
  int wave = threadIdx.x >> 6;
  int start = blockIdx.x*512 + wave*128;
  if(start >= n) return;
  int end = min(start+128, n);
  int cur = batch[start];
  float acc = 0.f;
  for(int i=start;i<end;i++){
    int bb = batch[i];
    if(bb != cur){ atomicAdd(&psum[cur*64+lane], acc); acc=0.f; cur=bb; }
    acc = fmaf(lnx[(size_t)i*64+lane], wv[i], acc);
  }
  atomicAdd(&psum[cur*64+lane], acc);
}

__global__ void k_mlp(const float* __restrict__ psum, const int* __restrict__ cnt,
                      const float* __restrict__ Ssum,
                      const float* __restrict__ M0W, const float* __restrict__ M0b,
                      const float* __restrict__ M1W, const float* __restrict__ M1b,
                      const float* __restrict__ M2W, const float* __restrict__ M2b,
                      float* __restrict__ out){
  int b = threadIdx.x;
  float S = Ssum[0];
  int cb = cnt[b]; if(cb<1) cb=1;
  float inv = 1.f/(S*(float)cb);
  float p[64];
  #pragma unroll
  for(int f=0;f<64;f++) p[f] = psum[b*64+f]*inv;
  float h1[32];
  #pragma unroll
  for(int j=0;j<32;j++){
    float a=M0b[j];
    #pragma unroll
    for(int f=0;f<64;f++) a = fmaf(p[f], M0W[f*32+j], a);
    h1[j]=fmaxf(a,0.f);
  }
  float h2[16];
  #pragma unroll
  for(int j=0;j<16;j++){
    float a=M1b[j];
    #pragma unroll
    for(int f=0;f<32;f++) a = fmaf(h1[f], M1W[f*16+j], a);
    h2[j]=fmaxf(a,0.f);
  }
  #pragma unroll
  for(int j=0;j<2;j++){
    float a=M2b[j];
    #pragma unroll
    for(int f=0;f<16;f++) a = fmaf(h2[f], M2W[f*2+j], a);
    out[b*2+j]=a;
  }
}

// ---------------- launch ----------------

extern "C" void kernel_launch(void* const* d_in, const int* in_sizes, int n_in,
                              void* d_out, int out_size, void* d_ws, size_t ws_size,
                              hipStream_t stream){
  const float* x   = (const float*)d_in[0];
  const int*   ei  = (const int*)d_in[1];
  const int* batch = (const int*)d_in[2];
  const float* W0=(const float*)d_in[3],  *b0=(const float*)d_in[4],  *g0=(const float*)d_in[5],  *be0=(const float*)d_in[6];
  const float* W1=(const float*)d_in[7],  *b1=(const float*)d_in[8],  *g1=(const float*)d_in[9],  *be1=(const float*)d_in[10];
  const float* W2=(const float*)d_in[11], *b2=(const float*)d_in[12], *g2=(const float*)d_in[13], *be2=(const float*)d_in[14];
  const float* ln_g=(const float*)d_in[15], *ln_b=(const float*)d_in[16], *att=(const float*)d_in[17];
  const float* M0W=(const float*)d_in[18], *M0b=(const float*)d_in[19];
  const float* M1W=(const float*)d_in[20], *M1b=(const float*)d_in[21];
  const float* M2W=(const float*)d_in[22], *M2b=(const float*)d_in[23];
  const int N = in_sizes[0]/128;
  const int E = in_sizes[1]/2;
  const int* srcv = ei;
  const int* dstv = ei + E;
  // magic for range-id = floor(d*8/N): M = ceil(8*2^40/N); exact for d < 2^17
  const unsigned long long Mdiv = ((8ULL<<40) + (unsigned long long)N - 1) / (unsigned long long)N;

  char* base = (char*)d_ws;
  size_t off = 0;
  auto alloc = [&](size_t bytes)->char*{ char* p = base+off; off = (off+bytes+255)&~(size_t)255; return p; };
  // zeroed region first
  int*   deg    = (int*)  alloc((size_t)N*4);
  int*   cnt    = (int*)  alloc(64*4);
  float* stats  = (float*)alloc(6*256*4);
  float* psum   = (float*)alloc(64*64*4);
  float* Ssum   = (float*)alloc(4);
  size_t zero_bytes = off;
  float* dinv   = (float*)alloc((size_t)N*4);
  int*   rowptr = (int*)  alloc(((size_t)N+1)*4);
  int*   cursor = (int*)  alloc((size_t)N*4);
  int*   bsum   = (int*)  alloc(128*4);
  float* bnsc   = (float*)alloc(3*256*4);
  float* bnsh   = (float*)alloc(3*256*4);
  unsigned short* Wh0 = (unsigned short*)alloc((size_t)128*256*2);
  unsigned short* Wl0 = (unsigned short*)alloc((size_t)128*256*2);
  unsigned short* Wh1 = (unsigned short*)alloc((size_t)256*128*2);
  unsigned short* Wl1 = (unsigned short*)alloc((size_t)256*128*2);
  unsigned short* Wh2 = (unsigned short*)alloc((size_t)128*64*2);
  unsigned short* Wl2 = (unsigned short*)alloc((size_t)128*64*2);
  int*   adj    = (int*)  alloc((size_t)E*4);
  _Float16* x16 = (_Float16*)alloc((size_t)N*128*2);
  _Float16* R16 = (_Float16*)alloc((size_t)N*128*2);   // agg outputs (layers 0,1)
  _Float16* P16 = (_Float16*)alloc((size_t)N*256*2);   // layer-0 pre-BN h
  _Float16* Q16 = (_Float16*)alloc((size_t)N*128*2);   // GEMM1/2 outputs
  _Float16* O16 = (_Float16*)alloc((size_t)N*64*2);    // layer-2 pre-BN h
  float* LNX    = (float*)alloc((size_t)N*64*4);
  float* WV     = (float*)alloc((size_t)N*4);
  (void)ws_size; (void)n_in; (void)out_size;

  hipMemsetAsync(d_ws, 0, zero_bytes, stream);

  // graph structure + weight prep
  k_deg_hist  <<<2048,256,0,stream>>>(dstv, deg, E, Mdiv);
  k_batch_hist<<<256,256,0,stream>>>(batch, cnt, N);
  k_dinv      <<<(N+255)/256,256,0,stream>>>(deg, dinv, N);
  int nblk = (N+1023)/1024;
  k_scan1<<<nblk,256,0,stream>>>(deg, bsum, N);
  k_scan2<<<1,128,0,stream>>>(bsum, nblk, rowptr, N);
  k_scan3<<<nblk,256,0,stream>>>(deg, bsum, rowptr, cursor, N);
  k_csr_fill<<<2048,256,0,stream>>>(srcv, dstv, cursor, adj, E, Mdiv);
  k_prep_w<<<(128*256+255)/256,256,0,stream>>>(W0, Wh0, Wl0, 128, 256);
  k_prep_w<<<(256*128+255)/256,256,0,stream>>>(W1, Wh1, Wl1, 256, 128);
  k_prep_w<<<(128*64 +255)/256,256,0,stream>>>(W2, Wh2, Wl2, 128, 64);
  k_prep_x<<<(N*32+255)/256,256,0,stream>>>(x, dinv, x16, N);

  const int gemm_grid = (N+127)/128;

  // ---- layer 0: R16 = agg(x*dinv); P16 = R16@W0 + b0; stats ----
  k_agg16<<<(N*16+255)/256,256,0,stream>>>(x16, rowptr, adj, dinv, nullptr, R16, N, 4);
  k_gemm_mfma<128,256,false,true,false,_Float16,_Float16><<<gemm_grid,256,0,stream>>>(R16, Wh0, Wl0, nullptr,nullptr, b0, nullptr, P16, N);
  k_bn_stats16<<<1024,256,0,stream>>>(P16, stats+0, stats+256, N, 8);
  k_bn_finalize<<<1,256,0,stream>>>(stats+0, stats+256, g0, be0, bnsc+0, bnsh+0, N, 256);

  // ---- layer 1: Q16 = relu(bn0(P16))@W1 * dinv; R16 = agg(Q16) + b1; stats ----
  k_gemm_mfma<256,128,true,false,true,_Float16,_Float16><<<gemm_grid,256,0,stream>>>(P16, Wh1, Wl1, bnsc+0, bnsh+0, nullptr, dinv, Q16, N);
  k_agg16<<<(N*16+255)/256,256,0,stream>>>(Q16, rowptr, adj, dinv, b1, R16, N, 4);
  k_bn_stats16<<<1024,256,0,stream>>>(R16, stats+512, stats+768, N, 7);
  k_bn_finalize<<<1,256,0,stream>>>(stats+512, stats+768, g1, be1, bnsc+256, bnsh+256, N, 128);

  // ---- layer 2: Q16 = relu(bn1(R16))@W2 * dinv; O16 = agg(Q16) + b2; stats ----
  k_gemm_mfma<128,64,true,false,true,_Float16,_Float16><<<gemm_grid,256,0,stream>>>(R16, Wh2, Wl2, bnsc+256, bnsh+256, nullptr, dinv, Q16, N);
  k_agg16<<<(N*8+255)/256,256,0,stream>>>(Q16, rowptr, adj, dinv, b2, O16, N, 3);
  k_bn_stats16<<<1024,256,0,stream>>>(O16, stats+1024, stats+1280, N, 6);
  k_bn_finalize<<<1,256,0,stream>>>(stats+1024, stats+1280, g2, be2, bnsc+512, bnsh+512, N, 64);

  // ---- head (BN2+relu fused into ln_att) ----
  k_ln_att<<<1024,256,0,stream>>>(O16, bnsc+512, bnsh+512, ln_g, ln_b, att, LNX, WV, Ssum, N);
  k_pool  <<<(N+511)/512,256,0,stream>>>(LNX, WV, batch, psum, N);
  k_mlp   <<<1,64,0,stream>>>(psum, cnt, Ssum, M0W,M0b,M1W,M1b,M2W,M2b, (float*)d_out);
}

// Round 7
// 788.466 us; speedup vs baseline: 1.5851x; 1.5851x over previous
//
#include <hip/hip_runtime.h>
#include <hip/hip_bf16.h>
#include <cstdint>
#include <cstddef>

typedef float    f32x4  __attribute__((ext_vector_type(4)));
typedef __bf16   bf16x8 __attribute__((ext_vector_type(8)));
typedef _Float16 f16x4  __attribute__((ext_vector_type(4)));
typedef _Float16 f16x8  __attribute__((ext_vector_type(8)));

#define BN_G1 1024   // stage-1 grid for bn stats

__device__ __forceinline__ unsigned short f2bf(float x){
  unsigned u = __float_as_uint(x);
  return (unsigned short)((u + 0x7fffu + ((u >> 16) & 1u)) >> 16);
}
__device__ __forceinline__ float bfhi(unsigned short h){
  return __uint_as_float(((unsigned)h) << 16);
}

// ---------------- graph structure ----------------
// XCD-filtered histogram: block b handles chunk b>>3, keeps dst with range-id == b&7.
__global__ void k_deg_hist(const int* __restrict__ dst, int* __restrict__ deg, int E,
                           unsigned long long M){
  int f   = blockIdx.x & 7;
  int cid = blockIdx.x >> 3;
  int nch = gridDim.x >> 3;
  for(int i = cid*blockDim.x + threadIdx.x; i < E; i += nch*blockDim.x){
    int d = dst[i];
    int xf = (int)(((unsigned long long)(unsigned)d * M) >> 40);
    if(xf == f) atomicAdd(&deg[d], 1);
  }
}

__global__ void k_batch_hist(const int* __restrict__ batch, int* __restrict__ cnt, int n){
  __shared__ int h[64];
  if(threadIdx.x<64) h[threadIdx.x]=0;
  __syncthreads();
  int i = blockIdx.x*blockDim.x + threadIdx.x;
  int stride = gridDim.x*blockDim.x;
  for(; i<n; i+=stride) atomicAdd(&h[batch[i]], 1);
  __syncthreads();
  if(threadIdx.x<64 && h[threadIdx.x]) atomicAdd(&cnt[threadIdx.x], h[threadIdx.x]);
}

__global__ void k_dinv(const int* __restrict__ deg, float* __restrict__ dinv, int n){
  int i = blockIdx.x*blockDim.x + threadIdx.x;
  if(i<n) dinv[i] = rsqrtf((float)(deg[i]+1));   // +1 = self loop
}

__global__ void k_scan1(const int* __restrict__ deg, int* __restrict__ bsum, int n){
  __shared__ int s[256];
  int base = blockIdx.x*1024 + threadIdx.x*4;
  int acc=0;
  #pragma unroll
  for(int j=0;j<4;j++){ int i=base+j; if(i<n) acc+=deg[i]; }
  s[threadIdx.x]=acc; __syncthreads();
  for(int off=128;off>0;off>>=1){
    if(threadIdx.x<off) s[threadIdx.x]+=s[threadIdx.x+off];
    __syncthreads();
  }
  if(threadIdx.x==0) bsum[blockIdx.x]=s[0];
}

__global__ void k_scan2(int* __restrict__ bsum, int nblk, int* __restrict__ rowptr, int n){
  __shared__ int s[128];
  int t=threadIdx.x;
  int v = (t<nblk)? bsum[t] : 0;
  s[t]=v; __syncthreads();
  for(int off=1; off<128; off<<=1){
    int a = (t>=off)? s[t-off] : 0;
    __syncthreads();
    s[t]+=a;
    __syncthreads();
  }
  if(t<nblk) bsum[t]=s[t]-v;         // exclusive block offsets
  if(t==127) rowptr[n]=s[127];       // total = E
}

__global__ void k_scan3(const int* __restrict__ deg, const int* __restrict__ bsum,
                        int* __restrict__ rowptr, int* __restrict__ cursor, int n){
  __shared__ int s[256];
  int base = blockIdx.x*1024 + threadIdx.x*4;
  int v[4]; int acc=0;
  #pragma unroll
  for(int j=0;j<4;j++){ int i=base+j; v[j]=(i<n)?deg[i]:0; acc+=v[j]; }
  s[threadIdx.x]=acc; __syncthreads();
  for(int off=1; off<256; off<<=1){
    int a = (threadIdx.x>=off)? s[threadIdx.x-off] : 0;
    __syncthreads();
    s[threadIdx.x]+=a;
    __syncthreads();
  }
  int excl = s[threadIdx.x]-acc + bsum[blockIdx.x];
  #pragma unroll
  for(int j=0;j<4;j++){
    int i=base+j;
    if(i<n){ rowptr[i]=excl; cursor[i]=excl; excl+=v[j]; }
  }
}

// XCD-filtered CSR fill
__global__ void k_csr_fill(const int* __restrict__ src, const int* __restrict__ dst,
                           int* __restrict__ cursor, int* __restrict__ adj, int E,
                           unsigned long long M){
  int f   = blockIdx.x & 7;
  int cid = blockIdx.x >> 3;
  int nch = gridDim.x >> 3;
  for(int i = cid*blockDim.x + threadIdx.x; i < E; i += nch*blockDim.x){
    int d = dst[i];
    int xf = (int)(((unsigned long long)(unsigned)d * M) >> 40);
    if(xf == f){
      int p = atomicAdd(&cursor[d], 1);
      adj[p] = src[i];
    }
  }
}

// ---------------- W preprocess: transpose + bf16 hi/lo split ----------------

__global__ void k_prep_w(const float* __restrict__ W, unsigned short* __restrict__ Wh,
                         unsigned short* __restrict__ Wl, int K, int F){
  int i = blockIdx.x*256 + threadIdx.x;
  if(i < K*F){
    int k = i / F, f = i % F;
    float a = W[i];
    unsigned short h = f2bf(a);
    Wh[(size_t)f*K + k] = h;
    Wl[(size_t)f*K + k] = f2bf(a - bfhi(h));
  }
}

// x16[node,f] = x[node,f] * dinv[node]  (fp16)
__global__ void k_prep_x(const float* __restrict__ x, const float* __restrict__ dinv,
                         _Float16* __restrict__ x16, int n){
  int tid = blockIdx.x*256 + threadIdx.x;
  int node = tid >> 5;
  if(node>=n) return;
  int c4 = tid & 31;
  size_t idx = ((size_t)node<<5) + c4;
  float4 v = ((const float4*)x)[idx];
  float d = dinv[node];
  f16x4 o;
  o[0]=(_Float16)(v.x*d); o[1]=(_Float16)(v.y*d); o[2]=(_Float16)(v.z*d); o[3]=(_Float16)(v.w*d);
  ((f16x4*)x16)[idx] = o;
}

// ---------------- aggregate (fp16 gather, fp32 accum, fp16 out) ----------------
// out[i] = dinv[i] * ( sum_{e:dst=i} z[src] + z[i] ) + bias;  F = 8<<lg8 feats
__global__ void k_agg16(const _Float16* __restrict__ zs, const int* __restrict__ rowptr,
                        const int* __restrict__ adj, const float* __restrict__ dinv,
                        const float* __restrict__ bias, _Float16* __restrict__ out,
                        int n, int lg8){
  int tid = blockIdx.x*blockDim.x + threadIdx.x;
  int node = tid >> lg8;
  if(node>=n) return;
  int c8 = tid & ((1<<lg8)-1);
  const f16x8* z8 = (const f16x8*)zs;
  size_t rb = ((size_t)node<<lg8) + c8;
  f16x8 self = z8[rb];
  float a0[8], a1[8];
  #pragma unroll
  for(int j=0;j<8;j++){ a0[j] = (float)self[j]; a1[j]=0.f; }
  int e = rowptr[node], end = rowptr[node+1];
  for(; e+1<end; e+=2){
    int s0=adj[e], s1=adj[e+1];
    f16x8 v0 = z8[((size_t)s0<<lg8)+c8];
    f16x8 v1 = z8[((size_t)s1<<lg8)+c8];
    #pragma unroll
    for(int j=0;j<8;j++){ a0[j]+=(float)v0[j]; a1[j]+=(float)v1[j]; }
  }
  if(e<end){
    f16x8 v0 = z8[((size_t)adj[e]<<lg8)+c8];
    #pragma unroll
    for(int j=0;j<8;j++) a0[j]+=(float)v0[j];
  }
  float di = dinv[node];
  f16x8 o;
  #pragma unroll
  for(int j=0;j<8;j++){
    float r = (a0[j]+a1[j])*di;
    if(bias) r += bias[(c8<<3)+j];
    o[j] = (_Float16)r;
  }
  ((f16x8*)out)[rb] = o;
}

// ---------------- MFMA GEMM with bf16 hi/lo split ----------------

template<typename AT> struct AFrag;
template<> struct AFrag<float>{
  float4 a,b;
  __device__ __forceinline__ void load(const float* p){ a=*(const float4*)p; b=*(const float4*)(p+4); }
  __device__ __forceinline__ void get(float o[8]) const {
    o[0]=a.x;o[1]=a.y;o[2]=a.z;o[3]=a.w;o[4]=b.x;o[5]=b.y;o[6]=b.z;o[7]=b.w;
  }
};
template<> struct AFrag<_Float16>{
  f16x8 v;
  __device__ __forceinline__ void load(const _Float16* p){ v=*(const f16x8*)p; }
  __device__ __forceinline__ void get(float o[8]) const {
    #pragma unroll
    for(int j=0;j<8;j++) o[j]=(float)v[j];
  }
};

// C[n,F] = act(A[n,K]) @ W[K,F]; act = BN? relu(A*sc+sh) : A
// W pre-transposed/split: Bh/Bl = bf16 [F][K]. Epilogue: +bias (BIAS), *rsc[row] (RSC).
template<int K, int F, bool BN, bool BIAS, bool RSC, typename AT, typename OT>
__global__ __launch_bounds__(256,2) void k_gemm_mfma(const AT* __restrict__ A,
    const unsigned short* __restrict__ Bh, const unsigned short* __restrict__ Bl,
    const float* __restrict__ sc, const float* __restrict__ sh,
    const float* __restrict__ bias, const float* __restrict__ rsc,
    OT* __restrict__ C, int n){
  constexpr int NF = F/16;
  const int l   = threadIdx.x & 63;
  const int w   = threadIdx.x >> 6;
  const int rlo = l & 15;            // A row within frag / C col within frag
  const int khi = l >> 4;            // k-group (0..3)
  const int row0 = blockIdx.x*128 + w*32;

  f32x4 acc[2][NF];
  #pragma unroll
  for(int i=0;i<2;i++)
    #pragma unroll
    for(int j=0;j<NF;j++) acc[i][j] = (f32x4){0.f,0.f,0.f,0.f};

  const size_t e0 = (size_t)min(row0 + rlo,      n-1) * K + khi*8;
  const size_t e1 = (size_t)min(row0 + 16 + rlo, n-1) * K + khi*8;

  AFrag<AT> c0,c1,x0f,x1f;
  c0.load(A + e0); c1.load(A + e1);

  #pragma unroll 1
  for(int k0=0; k0<K; k0+=32){
    if(k0+32 < K){
      x0f.load(A + e0 + k0 + 32);
      x1f.load(A + e1 + k0 + 32);
    }
    float scr[8], shr[8];
    if(BN){
      float4 s0 = *(const float4*)(sc + k0 + khi*8);
      float4 s1 = *(const float4*)(sc + k0 + khi*8 + 4);
      float4 t0 = *(const float4*)(sh + k0 + khi*8);
      float4 t1 = *(const float4*)(sh + k0 + khi*8 + 4);
      scr[0]=s0.x;scr[1]=s0.y;scr[2]=s0.z;scr[3]=s0.w;scr[4]=s1.x;scr[5]=s1.y;scr[6]=s1.z;scr[7]=s1.w;
      shr[0]=t0.x;shr[1]=t0.y;shr[2]=t0.z;shr[3]=t0.w;shr[4]=t1.x;shr[5]=t1.y;shr[6]=t1.z;shr[7]=t1.w;
    }
    union { unsigned short u[8]; bf16x8 v; } H0,L0,H1,L1;
    {
      float v0[8], v1[8];
      c0.get(v0); c1.get(v1);
      #pragma unroll
      for(int j=0;j<8;j++){
        float y0 = v0[j], y1 = v1[j];
        if(BN){ y0 = fmaxf(fmaf(y0,scr[j],shr[j]),0.f); y1 = fmaxf(fmaf(y1,scr[j],shr[j]),0.f); }
        unsigned short h0 = f2bf(y0), h1 = f2bf(y1);
        H0.u[j]=h0; L0.u[j]=f2bf(y0 - bfhi(h0));
        H1.u[j]=h1; L1.u[j]=f2bf(y1 - bfhi(h1));
      }
    }
    bf16x8 ah0=H0.v, al0=L0.v, ah1=H1.v, al1=L1.v;
    #pragma unroll
    for(int cf=0; cf<NF; cf++){
      size_t boff = (size_t)(cf*16 + rlo)*K + k0 + khi*8;
      bf16x8 bh = *(const bf16x8*)(Bh + boff);
      bf16x8 bl = *(const bf16x8*)(Bl + boff);
      acc[0][cf] = __builtin_amdgcn_mfma_f32_16x16x32_bf16(ah0, bh, acc[0][cf], 0,0,0);
      acc[1][cf] = __builtin_amdgcn_mfma_f32_16x16x32_bf16(ah1, bh, acc[1][cf], 0,0,0);
      acc[0][cf] = __builtin_amdgcn_mfma_f32_16x16x32_bf16(al0, bh, acc[0][cf], 0,0,0);
      acc[1][cf] = __builtin_amdgcn_mfma_f32_16x16x32_bf16(al1, bh, acc[1][cf], 0,0,0);
      acc[0][cf] = __builtin_amdgcn_mfma_f32_16x16x32_bf16(ah0, bl, acc[0][cf], 0,0,0);
      acc[1][cf] = __builtin_amdgcn_mfma_f32_16x16x32_bf16(ah1, bl, acc[1][cf], 0,0,0);
    }
    c0=x0f; c1=x1f;
  }

  // epilogue: C/D layout col=lane&15 (+16cf), row=(lane>>4)*4+reg (+16rf)
  #pragma unroll
  for(int rf=0; rf<2; rf++){
    #pragma unroll
    for(int r=0; r<4; r++){
      int m = row0 + rf*16 + khi*4 + r;
      if(m < n){
        float rs = RSC ? rsc[m] : 1.f;
        #pragma unroll
        for(int cf=0; cf<NF; cf++){
          int col = rlo + 16*cf;
          float v = acc[rf][cf][r];
          if(BIAS) v += bias[col];
          v *= rs;
          C[(size_t)m*F + col] = (OT)v;
        }
      }
    }
  }
}

// ---------------- BatchNorm stats: two-stage, atomic-free ----------------
// Stage 1: block writes per-column partial sums to partials[blk][2F] (coalesced).
__global__ __launch_bounds__(256) void k_bn_stats16(const _Float16* __restrict__ h,
                            float* __restrict__ partials, int n, int lgF){
  const int F   = 1 << lgF;
  const int C8  = 1 << (lgF-3);            // f16x8 chunks per row
  const int c8  = threadIdx.x & (C8-1);
  const int sub = threadIdx.x >> (lgF-3);
  const int rpb = 256 >> (lgF-3);          // rows per pass per block
  float s[8], s2[8];
  #pragma unroll
  for(int j=0;j<8;j++){ s[j]=0.f; s2[j]=0.f; }
  for(int row = blockIdx.x*rpb + sub; row < n; row += gridDim.x*rpb){
    f16x8 v = ((const f16x8*)h)[(size_t)row*C8 + c8];
    #pragma unroll
    for(int j=0;j<8;j++){ float f=(float)v[j]; s[j]+=f; s2[j]=fmaf(f,f,s2[j]); }
  }
  __shared__ float rs [256*9];
  __shared__ float rs2[256*9];
  #pragma unroll
  for(int j=0;j<8;j++){ rs[threadIdx.x*9+j]=s[j]; rs2[threadIdx.x*9+j]=s2[j]; }
  __syncthreads();
  for(int half = rpb>>1; half>=1; half>>=1){
    if(sub < half){
      int o = (threadIdx.x + half*C8)*9;
      #pragma unroll
      for(int j=0;j<8;j++){ rs[threadIdx.x*9+j]+=rs[o+j]; rs2[threadIdx.x*9+j]+=rs2[o+j]; }
    }
    __syncthreads();
  }
  if(sub==0){
    float* p = partials + (size_t)blockIdx.x*(2*F);
    #pragma unroll
    for(int j=0;j<8;j++){
      p[c8*8+j]     = rs [threadIdx.x*9+j];
      p[F + c8*8+j] = rs2[threadIdx.x*9+j];
    }
  }
}

// Stage 2: column c of stats = sum over BN_G1 partial rows. grid = 2F/64, block = 64.
__global__ void k_bn_colsum(const float* __restrict__ partials, float* __restrict__ out, int F2){
  int c = blockIdx.x*64 + threadIdx.x;
  float s = 0.f;
  #pragma unroll 8
  for(int b=0; b<BN_G1; b++) s += partials[(size_t)b*F2 + c];
  out[c] = s;
}

__global__ void k_bn_finalize(const float* __restrict__ sums, const float* __restrict__ sumsq,
                              const float* __restrict__ g, const float* __restrict__ be,
                              float* __restrict__ scale, float* __restrict__ shift, int n, int F){
  int f = threadIdx.x;
  if(f<F){
    float mu = sums[f]/(float)n;
    float var = sumsq[f]/(float)n - mu*mu;
    float sc = g[f]*rsqrtf(var+1e-5f);
    scale[f] = sc;
    shift[f] = fmaf(-mu, sc, be[f]);
  }
}

// ---------------- head: (BN2+relu) + LN + attention + pool + MLP ----------------

__global__ void k_ln_att(const _Float16* __restrict__ x, const float* __restrict__ bsc, const float* __restrict__ bsh,
                         const float* __restrict__ g, const float* __restrict__ b,
                         const float* __restrict__ att, float* __restrict__ lnx, float* __restrict__ wv,
                         float* __restrict__ Ssum, int n){
  int lane = threadIdx.x & 63;
  int wid = (blockIdx.x<<2) + (threadIdx.x>>6);
  float gl=g[lane], bl=b[lane], al=att[lane];
  float scl=bsc[lane], shl=bsh[lane];
  float wacc=0.f;
  for(int node=wid; node<n; node+=4096){
    float raw = (float)x[((size_t)node<<6)+lane];
    float v = fmaxf(fmaf(raw, scl, shl), 0.f);     // fused BN2 + relu
    float s=v;
    #pragma unroll
    for(int o=32;o>0;o>>=1) s += __shfl_xor(s,o);
    float mu = s*0.015625f;
    float d = v-mu;
    float q = d*d;
    #pragma unroll
    for(int o=32;o>0;o>>=1) q += __shfl_xor(q,o);
    float ln = d*rsqrtf(q*0.015625f + 1e-5f)*gl + bl;
    lnx[((size_t)node<<6)+lane] = ln;
    float a = ln*al;
    #pragma unroll
    for(int o=32;o>0;o>>=1) a += __shfl_xor(a,o);
    float wgt = expf(tanhf(a));
    if(lane==0) wv[node]=wgt;
    wacc += wgt;
  }
  __shared__ float sred[4];
  if(lane==0) sred[threadIdx.x>>6]=wacc;
  __syncthreads();
  if(threadIdx.x==0) atomicAdd(Ssum, sred[0]+sred[1]+sred[2]+sred[3]);
}

__global__ void k_pool(const float* __restrict__ lnx, const float* __restrict__ wv,
                       const int* __restrict__ batch, float* __restrict__ psum, int n){
  int lane = threadIdx.x & 63;
  int wave = threadIdx.x >> 6;
  int start = blockIdx.x*512 + wave*128;
  if(start >= n) return;
  int end = min(start+128, n);
  int cur = batch[start];
  float acc = 0.f;
  for(int i=start;i<end;i++){
    int bb = batch[i];
    if(bb != cur){ atomicAdd(&psum[cur*64+lane], acc); acc=0.f; cur=bb; }
    acc = fmaf(lnx[(size_t)i*64+lane], wv[i], acc);
  }
  atomicAdd(&psum[cur*64+lane], acc);
}

__global__ void k_mlp(const float* __restrict__ psum, const int* __restrict__ cnt,
                      const float* __restrict__ Ssum,
                      const float* __restrict__ M0W, const float* __restrict__ M0b,
                      const float* __restrict__ M1W, const float* __restrict__ M1b,
                      const float* __restrict__ M2W, const float* __restrict__ M2b,
                      float* __restrict__ out){
  int b = threadIdx.x;
  float S = Ssum[0];
  int cb = cnt[b]; if(cb<1) cb=1;
  float inv = 1.f/(S*(float)cb);
  float p[64];
  #pragma unroll
  for(int f=0;f<64;f++) p[f] = psum[b*64+f]*inv;
  float h1[32];
  #pragma unroll
  for(int j=0;j<32;j++){
    float a=M0b[j];
    #pragma unroll
    for(int f=0;f<64;f++) a = fmaf(p[f], M0W[f*32+j], a);
    h1[j]=fmaxf(a,0.f);
  }
  float h2[16];
  #pragma unroll
  for(int j=0;j<16;j++){
    float a=M1b[j];
    #pragma unroll
    for(int f=0;f<32;f++) a = fmaf(h1[f], M1W[f*16+j], a);
    h2[j]=fmaxf(a,0.f);
  }
  #pragma unroll
  for(int j=0;j<2;j++){
    float a=M2b[j];
    #pragma unroll
    for(int f=0;f<16;f++) a = fmaf(h2[f], M2W[f*2+j], a);
    out[b*2+j]=a;
  }
}

// ---------------- launch ----------------

extern "C" void kernel_launch(void* const* d_in, const int* in_sizes, int n_in,
                              void* d_out, int out_size, void* d_ws, size_t ws_size,
                              hipStream_t stream){
  const float* x   = (const float*)d_in[0];
  const int*   ei  = (const int*)d_in[1];
  const int* batch = (const int*)d_in[2];
  const float* W0=(const float*)d_in[3],  *b0=(const float*)d_in[4],  *g0=(const float*)d_in[5],  *be0=(const float*)d_in[6];
  const float* W1=(const float*)d_in[7],  *b1=(const float*)d_in[8],  *g1=(const float*)d_in[9],  *be1=(const float*)d_in[10];
  const float* W2=(const float*)d_in[11], *b2=(const float*)d_in[12], *g2=(const float*)d_in[13], *be2=(const float*)d_in[14];
  const float* ln_g=(const float*)d_in[15], *ln_b=(const float*)d_in[16], *att=(const float*)d_in[17];
  const float* M0W=(const float*)d_in[18], *M0b=(const float*)d_in[19];
  const float* M1W=(const float*)d_in[20], *M1b=(const float*)d_in[21];
  const float* M2W=(const float*)d_in[22], *M2b=(const float*)d_in[23];
  const int N = in_sizes[0]/128;
  const int E = in_sizes[1]/2;
  const int* srcv = ei;
  const int* dstv = ei + E;
  // magic for range-id = floor(d*8/N): M = ceil(8*2^40/N); exact for d < 2^17
  const unsigned long long Mdiv = ((8ULL<<40) + (unsigned long long)N - 1) / (unsigned long long)N;

  char* base = (char*)d_ws;
  size_t off = 0;
  auto alloc = [&](size_t bytes)->char*{ char* p = base+off; off = (off+bytes+255)&~(size_t)255; return p; };
  // zeroed region first
  int*   deg    = (int*)  alloc((size_t)N*4);
  int*   cnt    = (int*)  alloc(64*4);
  float* psum   = (float*)alloc(64*64*4);
  float* Ssum   = (float*)alloc(4);
  size_t zero_bytes = off;
  float* stats  = (float*)alloc(6*256*4);
  float* dinv   = (float*)alloc((size_t)N*4);
  int*   rowptr = (int*)  alloc(((size_t)N+1)*4);
  int*   cursor = (int*)  alloc((size_t)N*4);
  int*   bsum   = (int*)  alloc(128*4);
  float* bnsc   = (float*)alloc(3*256*4);
  float* bnsh   = (float*)alloc(3*256*4);
  float* partials = (float*)alloc((size_t)BN_G1*512*4);   // [G1][2F], F<=256
  unsigned short* Wh0 = (unsigned short*)alloc((size_t)128*256*2);
  unsigned short* Wl0 = (unsigned short*)alloc((size_t)128*256*2);
  unsigned short* Wh1 = (unsigned short*)alloc((size_t)256*128*2);
  unsigned short* Wl1 = (unsigned short*)alloc((size_t)256*128*2);
  unsigned short* Wh2 = (unsigned short*)alloc((size_t)128*64*2);
  unsigned short* Wl2 = (unsigned short*)alloc((size_t)128*64*2);
  int*   adj    = (int*)  alloc((size_t)E*4);
  _Float16* x16 = (_Float16*)alloc((size_t)N*128*2);
  _Float16* R16 = (_Float16*)alloc((size_t)N*128*2);   // agg outputs (layers 0,1)
  _Float16* P16 = (_Float16*)alloc((size_t)N*256*2);   // layer-0 pre-BN h
  _Float16* Q16 = (_Float16*)alloc((size_t)N*128*2);   // GEMM1/2 outputs
  _Float16* O16 = (_Float16*)alloc((size_t)N*64*2);    // layer-2 pre-BN h
  float* LNX    = (float*)alloc((size_t)N*64*4);
  float* WV     = (float*)alloc((size_t)N*4);
  (void)ws_size; (void)n_in; (void)out_size;

  hipMemsetAsync(d_ws, 0, zero_bytes, stream);

  // graph structure + weight prep
  k_deg_hist  <<<2048,256,0,stream>>>(dstv, deg, E, Mdiv);
  k_batch_hist<<<256,256,0,stream>>>(batch, cnt, N);
  k_dinv      <<<(N+255)/256,256,0,stream>>>(deg, dinv, N);
  int nblk = (N+1023)/1024;
  k_scan1<<<nblk,256,0,stream>>>(deg, bsum, N);
  k_scan2<<<1,128,0,stream>>>(bsum, nblk, rowptr, N);
  k_scan3<<<nblk,256,0,stream>>>(deg, bsum, rowptr, cursor, N);
  k_csr_fill<<<2048,256,0,stream>>>(srcv, dstv, cursor, adj, E, Mdiv);
  k_prep_w<<<(128*256+255)/256,256,0,stream>>>(W0, Wh0, Wl0, 128, 256);
  k_prep_w<<<(256*128+255)/256,256,0,stream>>>(W1, Wh1, Wl1, 256, 128);
  k_prep_w<<<(128*64 +255)/256,256,0,stream>>>(W2, Wh2, Wl2, 128, 64);
  k_prep_x<<<(N*32+255)/256,256,0,stream>>>(x, dinv, x16, N);

  const int gemm_grid = (N+127)/128;

  // ---- layer 0: R16 = agg(x*dinv); P16 = R16@W0 + b0; stats ----
  k_agg16<<<(N*16+255)/256,256,0,stream>>>(x16, rowptr, adj, dinv, nullptr, R16, N, 4);
  k_gemm_mfma<128,256,false,true,false,_Float16,_Float16><<<gemm_grid,256,0,stream>>>(R16, Wh0, Wl0, nullptr,nullptr, b0, nullptr, P16, N);
  k_bn_stats16<<<BN_G1,256,0,stream>>>(P16, partials, N, 8);
  k_bn_colsum<<<512/64,64,0,stream>>>(partials, stats+0, 512);
  k_bn_finalize<<<1,256,0,stream>>>(stats+0, stats+256, g0, be0, bnsc+0, bnsh+0, N, 256);

  // ---- layer 1: Q16 = relu(bn0(P16))@W1 * dinv; R16 = agg(Q16) + b1; stats ----
  k_gemm_mfma<256,128,true,false,true,_Float16,_Float16><<<gemm_grid,256,0,stream>>>(P16, Wh1, Wl1, bnsc+0, bnsh+0, nullptr, dinv, Q16, N);
  k_agg16<<<(N*16+255)/256,256,0,stream>>>(Q16, rowptr, adj, dinv, b1, R16, N, 4);
  k_bn_stats16<<<BN_G1,256,0,stream>>>(R16, partials, N, 7);
  k_bn_colsum<<<256/64,64,0,stream>>>(partials, stats+512, 256);
  k_bn_finalize<<<1,256,0,stream>>>(stats+512, stats+640, g1, be1, bnsc+256, bnsh+256, N, 128);

  // ---- layer 2: Q16 = relu(bn1(R16))@W2 * dinv; O16 = agg(Q16) + b2; stats ----
  k_gemm_mfma<128,64,true,false,true,_Float16,_Float16><<<gemm_grid,256,0,stream>>>(R16, Wh2, Wl2, bnsc+256, bnsh+256, nullptr, dinv, Q16, N);
  k_agg16<<<(N*8+255)/256,256,0,stream>>>(Q16, rowptr, adj, dinv, b2, O16, N, 3);
  k_bn_stats16<<<BN_G1,256,0,stream>>>(O16, partials, N, 6);
  k_bn_colsum<<<128/64,64,0,stream>>>(partials, stats+1024, 128);
  k_bn_finalize<<<1,256,0,stream>>>(stats+1024, stats+1088, g2, be2, bnsc+512, bnsh+512, N, 64);

  // ---- head (BN2+relu fused into ln_att) ----
  k_ln_att<<<1024,256,0,stream>>>(O16, bnsc+512, bnsh+512, ln_g, ln_b, att, LNX, WV, Ssum, N);
  k_pool  <<<(N+511)/512,256,0,stream>>>(LNX, WV, batch, psum, N);
  k_mlp   <<<1,64,0,stream>>>(psum, cnt, Ssum, M0W,M0b,M1W,M1b,M2W,M2b, (float*)d_out);
}

// Round 8
// 694.675 us; speedup vs baseline: 1.7991x; 1.1350x over previous
//
#include <hip/hip_runtime.h>
#include <hip/hip_bf16.h>
#include <cstdint>
#include <cstddef>

typedef float    f32x4  __attribute__((ext_vector_type(4)));
typedef __bf16   bf16x8 __attribute__((ext_vector_type(8)));
typedef _Float16 f16x4  __attribute__((ext_vector_type(4)));
typedef _Float16 f16x8  __attribute__((ext_vector_type(8)));

#define BN_G1 1024   // stage-1 grid for bn stats

__device__ __forceinline__ unsigned short f2bf(float x){
  unsigned u = __float_as_uint(x);
  return (unsigned short)((u + 0x7fffu + ((u >> 16) & 1u)) >> 16);
}
__device__ __forceinline__ float bfhi(unsigned short h){
  return __uint_as_float(((unsigned)h) << 16);
}

// ---------------- graph structure ----------------
// XCD-filtered histogram: block b handles chunk b>>3, keeps dst with range-id == b&7.
__global__ void k_deg_hist(const int* __restrict__ dst, int* __restrict__ deg, int E,
                           unsigned long long M){
  int f   = blockIdx.x & 7;
  int cid = blockIdx.x >> 3;
  int nch = gridDim.x >> 3;
  for(int i = cid*blockDim.x + threadIdx.x; i < E; i += nch*blockDim.x){
    int d = dst[i];
    int xf = (int)(((unsigned long long)(unsigned)d * M) >> 40);
    if(xf == f) atomicAdd(&deg[d], 1);
  }
}

__global__ void k_batch_hist(const int* __restrict__ batch, int* __restrict__ cnt, int n){
  __shared__ int h[64];
  if(threadIdx.x<64) h[threadIdx.x]=0;
  __syncthreads();
  int i = blockIdx.x*blockDim.x + threadIdx.x;
  int stride = gridDim.x*blockDim.x;
  for(; i<n; i+=stride) atomicAdd(&h[batch[i]], 1);
  __syncthreads();
  if(threadIdx.x<64 && h[threadIdx.x]) atomicAdd(&cnt[threadIdx.x], h[threadIdx.x]);
}

__global__ void k_dinv(const int* __restrict__ deg, float* __restrict__ dinv, int n){
  int i = blockIdx.x*blockDim.x + threadIdx.x;
  if(i<n) dinv[i] = rsqrtf((float)(deg[i]+1));   // +1 = self loop
}

__global__ void k_scan1(const int* __restrict__ deg, int* __restrict__ bsum, int n){
  __shared__ int s[256];
  int base = blockIdx.x*1024 + threadIdx.x*4;
  int acc=0;
  #pragma unroll
  for(int j=0;j<4;j++){ int i=base+j; if(i<n) acc+=deg[i]; }
  s[threadIdx.x]=acc; __syncthreads();
  for(int off=128;off>0;off>>=1){
    if(threadIdx.x<off) s[threadIdx.x]+=s[threadIdx.x+off];
    __syncthreads();
  }
  if(threadIdx.x==0) bsum[blockIdx.x]=s[0];
}

__global__ void k_scan2(int* __restrict__ bsum, int nblk, int* __restrict__ rowptr, int n){
  __shared__ int s[128];
  int t=threadIdx.x;
  int v = (t<nblk)? bsum[t] : 0;
  s[t]=v; __syncthreads();
  for(int off=1; off<128; off<<=1){
    int a = (t>=off)? s[t-off] : 0;
    __syncthreads();
    s[t]+=a;
    __syncthreads();
  }
  if(t<nblk) bsum[t]=s[t]-v;         // exclusive block offsets
  if(t==127) rowptr[n]=s[127];       // total = E
}

__global__ void k_scan3(const int* __restrict__ deg, const int* __restrict__ bsum,
                        int* __restrict__ rowptr, int* __restrict__ cursor, int n){
  __shared__ int s[256];
  int base = blockIdx.x*1024 + threadIdx.x*4;
  int v[4]; int acc=0;
  #pragma unroll
  for(int j=0;j<4;j++){ int i=base+j; v[j]=(i<n)?deg[i]:0; acc+=v[j]; }
  s[threadIdx.x]=acc; __syncthreads();
  for(int off=1; off<256; off<<=1){
    int a = (threadIdx.x>=off)? s[threadIdx.x-off] : 0;
    __syncthreads();
    s[threadIdx.x]+=a;
    __syncthreads();
  }
  int excl = s[threadIdx.x]-acc + bsum[blockIdx.x];
  #pragma unroll
  for(int j=0;j<4;j++){
    int i=base+j;
    if(i<n){ rowptr[i]=excl; cursor[i]=excl; excl+=v[j]; }
  }
}

// XCD-filtered CSR fill
__global__ void k_csr_fill(const int* __restrict__ src, const int* __restrict__ dst,
                           int* __restrict__ cursor, int* __restrict__ adj, int E,
                           unsigned long long M){
  int f   = blockIdx.x & 7;
  int cid = blockIdx.x >> 3;
  int nch = gridDim.x >> 3;
  for(int i = cid*blockDim.x + threadIdx.x; i < E; i += nch*blockDim.x){
    int d = dst[i];
    int xf = (int)(((unsigned long long)(unsigned)d * M) >> 40);
    if(xf == f){
      int p = atomicAdd(&cursor[d], 1);
      adj[p] = src[i];
    }
  }
}

// ---------------- W preprocess: transpose + bf16 hi/lo split ----------------

__global__ void k_prep_w(const float* __restrict__ W, unsigned short* __restrict__ Wh,
                         unsigned short* __restrict__ Wl, int K, int F){
  int i = blockIdx.x*256 + threadIdx.x;
  if(i < K*F){
    int k = i / F, f = i % F;
    float a = W[i];
    unsigned short h = f2bf(a);
    Wh[(size_t)f*K + k] = h;
    Wl[(size_t)f*K + k] = f2bf(a - bfhi(h));
  }
}

// x16[node,f] = x[node,f] * dinv[node]  (fp16)
__global__ void k_prep_x(const float* __restrict__ x, const float* __restrict__ dinv,
                         _Float16* __restrict__ x16, int n){
  int tid = blockIdx.x*256 + threadIdx.x;
  int node = tid >> 5;
  if(node>=n) return;
  int c4 = tid & 31;
  size_t idx = ((size_t)node<<5) + c4;
  float4 v = ((const float4*)x)[idx];
  float d = dinv[node];
  f16x4 o;
  o[0]=(_Float16)(v.x*d); o[1]=(_Float16)(v.y*d); o[2]=(_Float16)(v.z*d); o[3]=(_Float16)(v.w*d);
  ((f16x4*)x16)[idx] = o;
}

// ---------------- aggregate (fp16 gather, fp32 accum, fp16 out) ----------------
// out[i] = dinv[i] * ( sum_{e:dst=i} z[src] + z[i] ) + bias;  F = 8<<lg8 feats
__global__ void k_agg16(const _Float16* __restrict__ zs, const int* __restrict__ rowptr,
                        const int* __restrict__ adj, const float* __restrict__ dinv,
                        const float* __restrict__ bias, _Float16* __restrict__ out,
                        int n, int lg8){
  int tid = blockIdx.x*blockDim.x + threadIdx.x;
  int node = tid >> lg8;
  if(node>=n) return;
  int c8 = tid & ((1<<lg8)-1);
  const f16x8* z8 = (const f16x8*)zs;
  size_t rb = ((size_t)node<<lg8) + c8;
  f16x8 self = z8[rb];
  float a0[8], a1[8];
  #pragma unroll
  for(int j=0;j<8;j++){ a0[j] = (float)self[j]; a1[j]=0.f; }
  int e = rowptr[node], end = rowptr[node+1];
  for(; e+1<end; e+=2){
    int s0=adj[e], s1=adj[e+1];
    f16x8 v0 = z8[((size_t)s0<<lg8)+c8];
    f16x8 v1 = z8[((size_t)s1<<lg8)+c8];
    #pragma unroll
    for(int j=0;j<8;j++){ a0[j]+=(float)v0[j]; a1[j]+=(float)v1[j]; }
  }
  if(e<end){
    f16x8 v0 = z8[((size_t)adj[e]<<lg8)+c8];
    #pragma unroll
    for(int j=0;j<8;j++) a0[j]+=(float)v0[j];
  }
  float di = dinv[node];
  f16x8 o;
  #pragma unroll
  for(int j=0;j<8;j++){
    float r = (a0[j]+a1[j])*di;
    if(bias) r += bias[(c8<<3)+j];
    o[j] = (_Float16)r;
  }
  ((f16x8*)out)[rb] = o;
}

// ---------------- MFMA GEMM with bf16 hi/lo split + LDS-staged B ----------------

template<typename AT> struct AFrag;
template<> struct AFrag<float>{
  float4 a,b;
  __device__ __forceinline__ void load(const float* p){ a=*(const float4*)p; b=*(const float4*)(p+4); }
  __device__ __forceinline__ void get(float o[8]) const {
    o[0]=a.x;o[1]=a.y;o[2]=a.z;o[3]=a.w;o[4]=b.x;o[5]=b.y;o[6]=b.z;o[7]=b.w;
  }
};
template<> struct AFrag<_Float16>{
  f16x8 v;
  __device__ __forceinline__ void load(const _Float16* p){ v=*(const f16x8*)p; }
  __device__ __forceinline__ void get(float o[8]) const {
    #pragma unroll
    for(int j=0;j<8;j++) o[j]=(float)v[j];
  }
};

// C[n,F] = act(A[n,K]) @ W[K,F]; act = BN? relu(A*sc+sh) : A
// W pre-transposed/split: Bh/Bl = bf16 [F][K]. Epilogue: +bias (BIAS), *rsc[row] (RSC).
// B-tile staged in LDS per K-step, in fragment order: granule(cf,lane) = cf*64+lane.
template<int K, int F, bool BN, bool BIAS, bool RSC, typename AT, typename OT>
__global__ __launch_bounds__(256,2) void k_gemm_mfma(const AT* __restrict__ A,
    const unsigned short* __restrict__ Bh, const unsigned short* __restrict__ Bl,
    const float* __restrict__ sc, const float* __restrict__ sh,
    const float* __restrict__ bias, const float* __restrict__ rsc,
    OT* __restrict__ C, int n){
  constexpr int NF = F/16;
  __shared__ uint4 sBh[F*4];     // F rows x 32 k, 16B granules, fragment-ordered
  __shared__ uint4 sBl[F*4];
  const int l   = threadIdx.x & 63;
  const int w   = threadIdx.x >> 6;
  const int rlo = l & 15;            // A row within frag / C col within frag
  const int khi = l >> 4;            // k-group (0..3)
  const int row0 = blockIdx.x*128 + w*32;

  f32x4 acc[2][NF];
  #pragma unroll
  for(int i=0;i<2;i++)
    #pragma unroll
    for(int j=0;j<NF;j++) acc[i][j] = (f32x4){0.f,0.f,0.f,0.f};

  const size_t e0 = (size_t)min(row0 + rlo,      n-1) * K + khi*8;
  const size_t e1 = (size_t)min(row0 + 16 + rlo, n-1) * K + khi*8;

  AFrag<AT> c0,c1,x0f,x1f;
  c0.load(A + e0); c1.load(A + e1);

  #pragma unroll 1
  for(int k0=0; k0<K; k0+=32){
    if(k0+32 < K){
      x0f.load(A + e0 + k0 + 32);
      x1f.load(A + e1 + k0 + 32);
    }
    __syncthreads();     // previous tile fully consumed
    // stage B tile (hi+lo): global row f, 16B chunk kk8 -> granule (f>>4)*64 + kk8*16 + (f&15)
    #pragma unroll
    for(int j=0;j<F/64;j++){
      int i  = threadIdx.x + j*256;
      int f  = i >> 2;
      int k8 = i & 3;
      int g  = ((f>>4)<<6) + (k8<<4) + (f&15);
      size_t goff = (size_t)f*K + k0 + (k8<<3);
      sBh[g] = *(const uint4*)(Bh + goff);
      sBl[g] = *(const uint4*)(Bl + goff);
    }
    // convert current A fragments while staging loads are in flight
    float scr[8], shr[8];
    if(BN){
      float4 s0 = *(const float4*)(sc + k0 + khi*8);
      float4 s1 = *(const float4*)(sc + k0 + khi*8 + 4);
      float4 t0 = *(const float4*)(sh + k0 + khi*8);
      float4 t1 = *(const float4*)(sh + k0 + khi*8 + 4);
      scr[0]=s0.x;scr[1]=s0.y;scr[2]=s0.z;scr[3]=s0.w;scr[4]=s1.x;scr[5]=s1.y;scr[6]=s1.z;scr[7]=s1.w;
      shr[0]=t0.x;shr[1]=t0.y;shr[2]=t0.z;shr[3]=t0.w;shr[4]=t1.x;shr[5]=t1.y;shr[6]=t1.z;shr[7]=t1.w;
    }
    union { unsigned short u[8]; bf16x8 v; } H0,L0,H1,L1;
    {
      float v0[8], v1[8];
      c0.get(v0); c1.get(v1);
      #pragma unroll
      for(int j=0;j<8;j++){
        float y0 = v0[j], y1 = v1[j];
        if(BN){ y0 = fmaxf(fmaf(y0,scr[j],shr[j]),0.f); y1 = fmaxf(fmaf(y1,scr[j],shr[j]),0.f); }
        unsigned short h0 = f2bf(y0), h1 = f2bf(y1);
        H0.u[j]=h0; L0.u[j]=f2bf(y0 - bfhi(h0));
        H1.u[j]=h1; L1.u[j]=f2bf(y1 - bfhi(h1));
      }
    }
    bf16x8 ah0=H0.v, al0=L0.v, ah1=H1.v, al1=L1.v;
    __syncthreads();     // staging complete
    #pragma unroll
    for(int cf=0; cf<NF; cf++){
      bf16x8 bh = ((const bf16x8*)sBh)[cf*64 + l];   // stride-1 b128: conflict-free
      bf16x8 bl = ((const bf16x8*)sBl)[cf*64 + l];
      acc[0][cf] = __builtin_amdgcn_mfma_f32_16x16x32_bf16(ah0, bh, acc[0][cf], 0,0,0);
      acc[1][cf] = __builtin_amdgcn_mfma_f32_16x16x32_bf16(ah1, bh, acc[1][cf], 0,0,0);
      acc[0][cf] = __builtin_amdgcn_mfma_f32_16x16x32_bf16(al0, bh, acc[0][cf], 0,0,0);
      acc[1][cf] = __builtin_amdgcn_mfma_f32_16x16x32_bf16(al1, bh, acc[1][cf], 0,0,0);
      acc[0][cf] = __builtin_amdgcn_mfma_f32_16x16x32_bf16(ah0, bl, acc[0][cf], 0,0,0);
      acc[1][cf] = __builtin_amdgcn_mfma_f32_16x16x32_bf16(ah1, bl, acc[1][cf], 0,0,0);
    }
    c0=x0f; c1=x1f;
  }

  // epilogue: C/D layout col=lane&15 (+16cf), row=(lane>>4)*4+reg (+16rf)
  #pragma unroll
  for(int rf=0; rf<2; rf++){
    #pragma unroll
    for(int r=0; r<4; r++){
      int m = row0 + rf*16 + khi*4 + r;
      if(m < n){
        float rs = RSC ? rsc[m] : 1.f;
        #pragma unroll
        for(int cf=0; cf<NF; cf++){
          int col = rlo + 16*cf;
          float v = acc[rf][cf][r];
          if(BIAS) v += bias[col];
          v *= rs;
          C[(size_t)m*F + col] = (OT)v;
        }
      }
    }
  }
}

// ---------------- BatchNorm stats: two-stage, atomic-free ----------------
// Stage 1: block writes per-column partial sums to partials[blk][2F] (coalesced).
__global__ __launch_bounds__(256) void k_bn_stats16(const _Float16* __restrict__ h,
                            float* __restrict__ partials, int n, int lgF){
  const int F   = 1 << lgF;
  const int C8  = 1 << (lgF-3);            // f16x8 chunks per row
  const int c8  = threadIdx.x & (C8-1);
  const int sub = threadIdx.x >> (lgF-3);
  const int rpb = 256 >> (lgF-3);          // rows per pass per block
  float s[8], s2[8];
  #pragma unroll
  for(int j=0;j<8;j++){ s[j]=0.f; s2[j]=0.f; }
  for(int row = blockIdx.x*rpb + sub; row < n; row += gridDim.x*rpb){
    f16x8 v = ((const f16x8*)h)[(size_t)row*C8 + c8];
    #pragma unroll
    for(int j=0;j<8;j++){ float f=(float)v[j]; s[j]+=f; s2[j]=fmaf(f,f,s2[j]); }
  }
  __shared__ float rs [256*9];
  __shared__ float rs2[256*9];
  #pragma unroll
  for(int j=0;j<8;j++){ rs[threadIdx.x*9+j]=s[j]; rs2[threadIdx.x*9+j]=s2[j]; }
  __syncthreads();
  for(int half = rpb>>1; half>=1; half>>=1){
    if(sub < half){
      int o = (threadIdx.x + half*C8)*9;
      #pragma unroll
      for(int j=0;j<8;j++){ rs[threadIdx.x*9+j]+=rs[o+j]; rs2[threadIdx.x*9+j]+=rs2[o+j]; }
    }
    __syncthreads();
  }
  if(sub==0){
    float* p = partials + (size_t)blockIdx.x*(2*F);
    #pragma unroll
    for(int j=0;j<8;j++){
      p[c8*8+j]     = rs [threadIdx.x*9+j];
      p[F + c8*8+j] = rs2[threadIdx.x*9+j];
    }
  }
}

// Stage 2: column c of stats = sum over BN_G1 partial rows. grid = 2F/64, block = 64.
__global__ void k_bn_colsum(const float* __restrict__ partials, float* __restrict__ out, int F2){
  int c = blockIdx.x*64 + threadIdx.x;
  float s = 0.f;
  #pragma unroll 8
  for(int b=0; b<BN_G1; b++) s += partials[(size_t)b*F2 + c];
  out[c] = s;
}

__global__ void k_bn_finalize(const float* __restrict__ sums, const float* __restrict__ sumsq,
                              const float* __restrict__ g, const float* __restrict__ be,
                              float* __restrict__ scale, float* __restrict__ shift, int n, int F){
  int f = threadIdx.x;
  if(f<F){
    float mu = sums[f]/(float)n;
    float var = sumsq[f]/(float)n - mu*mu;
    float sc = g[f]*rsqrtf(var+1e-5f);
    scale[f] = sc;
    shift[f] = fmaf(-mu, sc, be[f]);
  }
}

// ---------------- head: (BN2+relu) + LN + attention + pool + MLP ----------------

__global__ void k_ln_att(const _Float16* __restrict__ x, const float* __restrict__ bsc, const float* __restrict__ bsh,
                         const float* __restrict__ g, const float* __restrict__ b,
                         const float* __restrict__ att, float* __restrict__ lnx, float* __restrict__ wv,
                         float* __restrict__ Ssum, int n){
  int lane = threadIdx.x & 63;
  int wid = (blockIdx.x<<2) + (threadIdx.x>>6);
  float gl=g[lane], bl=b[lane], al=att[lane];
  float scl=bsc[lane], shl=bsh[lane];
  float wacc=0.f;
  for(int node=wid; node<n; node+=4096){
    float raw = (float)x[((size_t)node<<6)+lane];
    float v = fmaxf(fmaf(raw, scl, shl), 0.f);     // fused BN2 + relu
    float s=v;
    #pragma unroll
    for(int o=32;o>0;o>>=1) s += __shfl_xor(s,o);
    float mu = s*0.015625f;
    float d = v-mu;
    float q = d*d;
    #pragma unroll
    for(int o=32;o>0;o>>=1) q += __shfl_xor(q,o);
    float ln = d*rsqrtf(q*0.015625f + 1e-5f)*gl + bl;
    lnx[((size_t)node<<6)+lane] = ln;
    float a = ln*al;
    #pragma unroll
    for(int o=32;o>0;o>>=1) a += __shfl_xor(a,o);
    float wgt = expf(tanhf(a));
    if(lane==0) wv[node]=wgt;
    wacc += wgt;
  }
  __shared__ float sred[4];
  if(lane==0) sred[threadIdx.x>>6]=wacc;
  __syncthreads();
  if(threadIdx.x==0) atomicAdd(Ssum, sred[0]+sred[1]+sred[2]+sred[3]);
}

__global__ void k_pool(const float* __restrict__ lnx, const float* __restrict__ wv,
                       const int* __restrict__ batch, float* __restrict__ psum, int n){
  int lane = threadIdx.x & 63;
  int wave = threadIdx.x >> 6;
  int start = blockIdx.x*512 + wave*128;
  if(start >= n) return;
  int end = min(start+128, n);
  int cur = batch[start];
  float acc = 0.f;
  for(int i=start;i<end;i++){
    int bb = batch[i];
    if(bb != cur){ atomicAdd(&psum[cur*64+lane], acc); acc=0.f; cur=bb; }
    acc = fmaf(lnx[(size_t)i*64+lane], wv[i], acc);
  }
  atomicAdd(&psum[cur*64+lane], acc);
}

__global__ void k_mlp(const float* __restrict__ psum, const int* __restrict__ cnt,
                      const float* __restrict__ Ssum,
                      const float* __restrict__ M0W, const float* __restrict__ M0b,
                      const float* __restrict__ M1W, const float* __restrict__ M1b,
                      const float* __restrict__ M2W, const float* __restrict__ M2b,
                      float* __restrict__ out){
  int b = threadIdx.x;
  float S = Ssum[0];
  int cb = cnt[b]; if(cb<1) cb=1;
  float inv = 1.f/(S*(float)cb);
  float p[64];
  #pragma unroll
  for(int f=0;f<64;f++) p[f] = psum[b*64+f]*inv;
  float h1[32];
  #pragma unroll
  for(int j=0;j<32;j++){
    float a=M0b[j];
    #pragma unroll
    for(int f=0;f<64;f++) a = fmaf(p[f], M0W[f*32+j], a);
    h1[j]=fmaxf(a,0.f);
  }
  float h2[16];
  #pragma unroll
  for(int j=0;j<16;j++){
    float a=M1b[j];
    #pragma unroll
    for(int f=0;f<32;f++) a = fmaf(h1[f], M1W[f*16+j], a);
    h2[j]=fmaxf(a,0.f);
  }
  #pragma unroll
  for(int j=0;j<2;j++){
    float a=M2b[j];
    #pragma unroll
    for(int f=0;f<16;f++) a = fmaf(h2[f], M2W[f*2+j], a);
    out[b*2+j]=a;
  }
}

// ---------------- launch ----------------

extern "C" void kernel_launch(void* const* d_in, const int* in_sizes, int n_in,
                              void* d_out, int out_size, void* d_ws, size_t ws_size,
                              hipStream_t stream){
  const float* x   = (const float*)d_in[0];
  const int*   ei  = (const int*)d_in[1];
  const int* batch = (const int*)d_in[2];
  const float* W0=(const float*)d_in[3],  *b0=(const float*)d_in[4],  *g0=(const float*)d_in[5],  *be0=(const float*)d_in[6];
  const float* W1=(const float*)d_in[7],  *b1=(const float*)d_in[8],  *g1=(const float*)d_in[9],  *be1=(const float*)d_in[10];
  const float* W2=(const float*)d_in[11], *b2=(const float*)d_in[12], *g2=(const float*)d_in[13], *be2=(const float*)d_in[14];
  const float* ln_g=(const float*)d_in[15], *ln_b=(const float*)d_in[16], *att=(const float*)d_in[17];
  const float* M0W=(const float*)d_in[18], *M0b=(const float*)d_in[19];
  const float* M1W=(const float*)d_in[20], *M1b=(const float*)d_in[21];
  const float* M2W=(const float*)d_in[22], *M2b=(const float*)d_in[23];
  const int N = in_sizes[0]/128;
  const int E = in_sizes[1]/2;
  const int* srcv = ei;
  const int* dstv = ei + E;
  // magic for range-id = floor(d*8/N): M = ceil(8*2^40/N); exact for d < 2^17
  const unsigned long long Mdiv = ((8ULL<<40) + (unsigned long long)N - 1) / (unsigned long long)N;

  char* base = (char*)d_ws;
  size_t off = 0;
  auto alloc = [&](size_t bytes)->char*{ char* p = base+off; off = (off+bytes+255)&~(size_t)255; return p; };
  // zeroed region first
  int*   deg    = (int*)  alloc((size_t)N*4);
  int*   cnt    = (int*)  alloc(64*4);
  float* psum   = (float*)alloc(64*64*4);
  float* Ssum   = (float*)alloc(4);
  size_t zero_bytes = off;
  float* stats  = (float*)alloc(6*256*4);
  float* dinv   = (float*)alloc((size_t)N*4);
  int*   rowptr = (int*)  alloc(((size_t)N+1)*4);
  int*   cursor = (int*)  alloc((size_t)N*4);
  int*   bsum   = (int*)  alloc(128*4);
  float* bnsc   = (float*)alloc(3*256*4);
  float* bnsh   = (float*)alloc(3*256*4);
  float* partials = (float*)alloc((size_t)BN_G1*512*4);   // [G1][2F], F<=256
  unsigned short* Wh0 = (unsigned short*)alloc((size_t)128*256*2);
  unsigned short* Wl0 = (unsigned short*)alloc((size_t)128*256*2);
  unsigned short* Wh1 = (unsigned short*)alloc((size_t)256*128*2);
  unsigned short* Wl1 = (unsigned short*)alloc((size_t)256*128*2);
  unsigned short* Wh2 = (unsigned short*)alloc((size_t)128*64*2);
  unsigned short* Wl2 = (unsigned short*)alloc((size_t)128*64*2);
  int*   adj    = (int*)  alloc((size_t)E*4);
  _Float16* x16 = (_Float16*)alloc((size_t)N*128*2);
  _Float16* R16 = (_Float16*)alloc((size_t)N*128*2);   // agg outputs (layers 0,1)
  _Float16* P16 = (_Float16*)alloc((size_t)N*256*2);   // layer-0 pre-BN h
  _Float16* Q16 = (_Float16*)alloc((size_t)N*128*2);   // GEMM1/2 outputs
  _Float16* O16 = (_Float16*)alloc((size_t)N*64*2);    // layer-2 pre-BN h
  float* LNX    = (float*)alloc((size_t)N*64*4);
  float* WV     = (float*)alloc((size_t)N*4);
  (void)ws_size; (void)n_in; (void)out_size;

  hipMemsetAsync(d_ws, 0, zero_bytes, stream);

  // graph structure + weight prep
  k_deg_hist  <<<2048,256,0,stream>>>(dstv, deg, E, Mdiv);
  k_batch_hist<<<256,256,0,stream>>>(batch, cnt, N);
  k_dinv      <<<(N+255)/256,256,0,stream>>>(deg, dinv, N);
  int nblk = (N+1023)/1024;
  k_scan1<<<nblk,256,0,stream>>>(deg, bsum, N);
  k_scan2<<<1,128,0,stream>>>(bsum, nblk, rowptr, N);
  k_scan3<<<nblk,256,0,stream>>>(deg, bsum, rowptr, cursor, N);
  k_csr_fill<<<2048,256,0,stream>>>(srcv, dstv, cursor, adj, E, Mdiv);
  k_prep_w<<<(128*256+255)/256,256,0,stream>>>(W0, Wh0, Wl0, 128, 256);
  k_prep_w<<<(256*128+255)/256,256,0,stream>>>(W1, Wh1, Wl1, 256, 128);
  k_prep_w<<<(128*64 +255)/256,256,0,stream>>>(W2, Wh2, Wl2, 128, 64);
  k_prep_x<<<(N*32+255)/256,256,0,stream>>>(x, dinv, x16, N);

  const int gemm_grid = (N+127)/128;

  // ---- layer 0: R16 = agg(x*dinv); P16 = R16@W0 + b0; stats ----
  k_agg16<<<(N*16+255)/256,256,0,stream>>>(x16, rowptr, adj, dinv, nullptr, R16, N, 4);
  k_gemm_mfma<128,256,false,true,false,_Float16,_Float16><<<gemm_grid,256,0,stream>>>(R16, Wh0, Wl0, nullptr,nullptr, b0, nullptr, P16, N);
  k_bn_stats16<<<BN_G1,256,0,stream>>>(P16, partials, N, 8);
  k_bn_colsum<<<512/64,64,0,stream>>>(partials, stats+0, 512);
  k_bn_finalize<<<1,256,0,stream>>>(stats+0, stats+256, g0, be0, bnsc+0, bnsh+0, N, 256);

  // ---- layer 1: Q16 = relu(bn0(P16))@W1 * dinv; R16 = agg(Q16) + b1; stats ----
  k_gemm_mfma<256,128,true,false,true,_Float16,_Float16><<<gemm_grid,256,0,stream>>>(P16, Wh1, Wl1, bnsc+0, bnsh+0, nullptr, dinv, Q16, N);
  k_agg16<<<(N*16+255)/256,256,0,stream>>>(Q16, rowptr, adj, dinv, b1, R16, N, 4);
  k_bn_stats16<<<BN_G1,256,0,stream>>>(R16, partials, N, 7);
  k_bn_colsum<<<256/64,64,0,stream>>>(partials, stats+512, 256);
  k_bn_finalize<<<1,256,0,stream>>>(stats+512, stats+640, g1, be1, bnsc+256, bnsh+256, N, 128);

  // ---- layer 2: Q16 = relu(bn1(R16))@W2 * dinv; O16 = agg(Q16) + b2; stats ----
  k_gemm_mfma<128,64,true,false,true,_Float16,_Float16><<<gemm_grid,256,0,stream>>>(R16, Wh2, Wl2, bnsc+256, bnsh+256, nullptr, dinv, Q16, N);
  k_agg16<<<(N*8+255)/256,256,0,stream>>>(Q16, rowptr, adj, dinv, b2, O16, N, 3);
  k_bn_stats16<<<BN_G1,256,0,stream>>>(O16, partials, N, 6);
  k_bn_colsum<<<128/64,64,0,stream>>>(partials, stats+1024, 128);
  k_bn_finalize<<<1,256,0,stream>>>(stats+1024, stats+1088, g2, be2, bnsc+512, bnsh+512, N, 64);

  // ---- head (BN2+relu fused into ln_att) ----
  k_ln_att<<<1024,256,0,stream>>>(O16, bnsc+512, bnsh+512, ln_g, ln_b, att, LNX, WV, Ssum, N);
  k_pool  <<<(N+511)/512,256,0,stream>>>(LNX, WV, batch, psum, N);
  k_mlp   <<<1,64,0,stream>>>(psum, cnt, Ssum, M0W,M0b,M1W,M1b,M2W,M2b, (float*)d_out);
}

// Round 9
// 685.709 us; speedup vs baseline: 1.8226x; 1.0131x over previous
//
#include <hip/hip_runtime.h>
#include <hip/hip_bf16.h>
#include <cstdint>
#include <cstddef>

typedef float    f32x4  __attribute__((ext_vector_type(4)));
typedef __bf16   bf16x8 __attribute__((ext_vector_type(8)));
typedef _Float16 f16x4  __attribute__((ext_vector_type(4)));
typedef _Float16 f16x8  __attribute__((ext_vector_type(8)));

#define BN_G1 1024   // stage-1 grid for bn stats

__device__ __forceinline__ unsigned short f2bf(float x){
  unsigned u = __float_as_uint(x);
  return (unsigned short)((u + 0x7fffu + ((u >> 16) & 1u)) >> 16);
}
__device__ __forceinline__ float bfhi(unsigned short h){
  return __uint_as_float(((unsigned)h) << 16);
}

// ---------------- graph structure ----------------
// XCD-filtered histogram: block b handles chunk b>>3, keeps dst with range-id == b&7.
__global__ void k_deg_hist(const int* __restrict__ dst, int* __restrict__ deg, int E,
                           unsigned long long M){
  int f   = blockIdx.x & 7;
  int cid = blockIdx.x >> 3;
  int nch = gridDim.x >> 3;
  for(int i = cid*blockDim.x + threadIdx.x; i < E; i += nch*blockDim.x){
    int d = dst[i];
    int xf = (int)(((unsigned long long)(unsigned)d * M) >> 40);
    if(xf == f) atomicAdd(&deg[d], 1);
  }
}

__global__ void k_batch_hist(const int* __restrict__ batch, int* __restrict__ cnt, int n){
  __shared__ int h[64];
  if(threadIdx.x<64) h[threadIdx.x]=0;
  __syncthreads();
  int i = blockIdx.x*blockDim.x + threadIdx.x;
  int stride = gridDim.x*blockDim.x;
  for(; i<n; i+=stride) atomicAdd(&h[batch[i]], 1);
  __syncthreads();
  if(threadIdx.x<64 && h[threadIdx.x]) atomicAdd(&cnt[threadIdx.x], h[threadIdx.x]);
}

__global__ void k_dinv(const int* __restrict__ deg, float* __restrict__ dinv, int n){
  int i = blockIdx.x*blockDim.x + threadIdx.x;
  if(i<n) dinv[i] = rsqrtf((float)(deg[i]+1));   // +1 = self loop
}

__global__ void k_scan1(const int* __restrict__ deg, int* __restrict__ bsum, int n){
  __shared__ int s[256];
  int base = blockIdx.x*1024 + threadIdx.x*4;
  int acc=0;
  #pragma unroll
  for(int j=0;j<4;j++){ int i=base+j; if(i<n) acc+=deg[i]; }
  s[threadIdx.x]=acc; __syncthreads();
  for(int off=128;off>0;off>>=1){
    if(threadIdx.x<off) s[threadIdx.x]+=s[threadIdx.x+off];
    __syncthreads();
  }
  if(threadIdx.x==0) bsum[blockIdx.x]=s[0];
}

__global__ void k_scan2(int* __restrict__ bsum, int nblk, int* __restrict__ rowptr, int n){
  __shared__ int s[128];
  int t=threadIdx.x;
  int v = (t<nblk)? bsum[t] : 0;
  s[t]=v; __syncthreads();
  for(int off=1; off<128; off<<=1){
    int a = (t>=off)? s[t-off] : 0;
    __syncthreads();
    s[t]+=a;
    __syncthreads();
  }
  if(t<nblk) bsum[t]=s[t]-v;         // exclusive block offsets
  if(t==127) rowptr[n]=s[127];       // total = E
}

__global__ void k_scan3(const int* __restrict__ deg, const int* __restrict__ bsum,
                        int* __restrict__ rowptr, int* __restrict__ cursor, int n){
  __shared__ int s[256];
  int base = blockIdx.x*1024 + threadIdx.x*4;
  int v[4]; int acc=0;
  #pragma unroll
  for(int j=0;j<4;j++){ int i=base+j; v[j]=(i<n)?deg[i]:0; acc+=v[j]; }
  s[threadIdx.x]=acc; __syncthreads();
  for(int off=1; off<256; off<<=1){
    int a = (threadIdx.x>=off)? s[threadIdx.x-off] : 0;
    __syncthreads();
    s[threadIdx.x]+=a;
    __syncthreads();
  }
  int excl = s[threadIdx.x]-acc + bsum[blockIdx.x];
  #pragma unroll
  for(int j=0;j<4;j++){
    int i=base+j;
    if(i<n){ rowptr[i]=excl; cursor[i]=excl; excl+=v[j]; }
  }
}

// XCD-filtered CSR fill
__global__ void k_csr_fill(const int* __restrict__ src, const int* __restrict__ dst,
                           int* __restrict__ cursor, int* __restrict__ adj, int E,
                           unsigned long long M){
  int f   = blockIdx.x & 7;
  int cid = blockIdx.x >> 3;
  int nch = gridDim.x >> 3;
  for(int i = cid*blockDim.x + threadIdx.x; i < E; i += nch*blockDim.x){
    int d = dst[i];
    int xf = (int)(((unsigned long long)(unsigned)d * M) >> 40);
    if(xf == f){
      int p = atomicAdd(&cursor[d], 1);
      adj[p] = src[i];
    }
  }
}

// ---------------- W preprocess: transpose + bf16 hi/lo split ----------------

__global__ void k_prep_w(const float* __restrict__ W, unsigned short* __restrict__ Wh,
                         unsigned short* __restrict__ Wl, int K, int F){
  int i = blockIdx.x*256 + threadIdx.x;
  if(i < K*F){
    int k = i / F, f = i % F;
    float a = W[i];
    unsigned short h = f2bf(a);
    Wh[(size_t)f*K + k] = h;
    Wl[(size_t)f*K + k] = f2bf(a - bfhi(h));
  }
}

// x16[node,f] = x[node,f] * dinv[node]  (fp16)
__global__ void k_prep_x(const float* __restrict__ x, const float* __restrict__ dinv,
                         _Float16* __restrict__ x16, int n){
  int tid = blockIdx.x*256 + threadIdx.x;
  int node = tid >> 5;
  if(node>=n) return;
  int c4 = tid & 31;
  size_t idx = ((size_t)node<<5) + c4;
  float4 v = ((const float4*)x)[idx];
  float d = dinv[node];
  f16x4 o;
  o[0]=(_Float16)(v.x*d); o[1]=(_Float16)(v.y*d); o[2]=(_Float16)(v.z*d); o[3]=(_Float16)(v.w*d);
  ((f16x4*)x16)[idx] = o;
}

// ---------------- aggregate (fp16 gather, fp32 accum, fp16 out) ----------------
// out[i] = dinv[i] * ( sum_{e:dst=i} z[src] + z[i] ) + bias;  F = 8<<lg8 feats
// 4-deep unrolled gather: 4 independent 64B-line misses in flight per thread.
__global__ void k_agg16(const _Float16* __restrict__ zs, const int* __restrict__ rowptr,
                        const int* __restrict__ adj, const float* __restrict__ dinv,
                        const float* __restrict__ bias, _Float16* __restrict__ out,
                        int n, int lg8){
  int tid = blockIdx.x*blockDim.x + threadIdx.x;
  int node = tid >> lg8;
  if(node>=n) return;
  int c8 = tid & ((1<<lg8)-1);
  const f16x8* z8 = (const f16x8*)zs;
  size_t rb = ((size_t)node<<lg8) + c8;
  f16x8 self = z8[rb];
  float a0[8], a1[8], a2[8], a3[8];
  #pragma unroll
  for(int j=0;j<8;j++){ a0[j]=(float)self[j]; a1[j]=0.f; a2[j]=0.f; a3[j]=0.f; }
  int e = rowptr[node], end = rowptr[node+1];
  for(; e+3<end; e+=4){
    int s0=adj[e], s1=adj[e+1], s2=adj[e+2], s3=adj[e+3];
    f16x8 v0 = z8[((size_t)s0<<lg8)+c8];
    f16x8 v1 = z8[((size_t)s1<<lg8)+c8];
    f16x8 v2 = z8[((size_t)s2<<lg8)+c8];
    f16x8 v3 = z8[((size_t)s3<<lg8)+c8];
    #pragma unroll
    for(int j=0;j<8;j++){
      a0[j]+=(float)v0[j]; a1[j]+=(float)v1[j];
      a2[j]+=(float)v2[j]; a3[j]+=(float)v3[j];
    }
  }
  for(; e<end; e++){
    f16x8 v0 = z8[((size_t)adj[e]<<lg8)+c8];
    #pragma unroll
    for(int j=0;j<8;j++) a0[j]+=(float)v0[j];
  }
  float di = dinv[node];
  f16x8 o;
  #pragma unroll
  for(int j=0;j<8;j++){
    float r = ((a0[j]+a1[j])+(a2[j]+a3[j]))*di;
    if(bias) r += bias[(c8<<3)+j];
    o[j] = (_Float16)r;
  }
  ((f16x8*)out)[rb] = o;
}

// ---------------- MFMA GEMM with bf16 hi/lo split + LDS-staged B ----------------

template<typename AT> struct AFrag;
template<> struct AFrag<float>{
  float4 a,b;
  __device__ __forceinline__ void load(const float* p){ a=*(const float4*)p; b=*(const float4*)(p+4); }
  __device__ __forceinline__ void get(float o[8]) const {
    o[0]=a.x;o[1]=a.y;o[2]=a.z;o[3]=a.w;o[4]=b.x;o[5]=b.y;o[6]=b.z;o[7]=b.w;
  }
};
template<> struct AFrag<_Float16>{
  f16x8 v;
  __device__ __forceinline__ void load(const _Float16* p){ v=*(const f16x8*)p; }
  __device__ __forceinline__ void get(float o[8]) const {
    #pragma unroll
    for(int j=0;j<8;j++) o[j]=(float)v[j];
  }
};

// C[n,F] = act(A[n,K]) @ W[K,F]; act = BN? relu(A*sc+sh) : A
// W pre-transposed/split: Bh/Bl = bf16 [F][K]. Epilogue: +bias (BIAS), *rsc[row] (RSC).
// B-tile staged in LDS per K-step, in fragment order: granule(cf,lane) = cf*64+lane.
template<int K, int F, bool BN, bool BIAS, bool RSC, typename AT, typename OT>
__global__ __launch_bounds__(256,2) void k_gemm_mfma(const AT* __restrict__ A,
    const unsigned short* __restrict__ Bh, const unsigned short* __restrict__ Bl,
    const float* __restrict__ sc, const float* __restrict__ sh,
    const float* __restrict__ bias, const float* __restrict__ rsc,
    OT* __restrict__ C, int n){
  constexpr int NF = F/16;
  __shared__ uint4 sBh[F*4];     // F rows x 32 k, 16B granules, fragment-ordered
  __shared__ uint4 sBl[F*4];
  const int l   = threadIdx.x & 63;
  const int w   = threadIdx.x >> 6;
  const int rlo = l & 15;            // A row within frag / C col within frag
  const int khi = l >> 4;            // k-group (0..3)
  const int row0 = blockIdx.x*128 + w*32;

  f32x4 acc[2][NF];
  #pragma unroll
  for(int i=0;i<2;i++)
    #pragma unroll
    for(int j=0;j<NF;j++) acc[i][j] = (f32x4){0.f,0.f,0.f,0.f};

  const size_t e0 = (size_t)min(row0 + rlo,      n-1) * K + khi*8;
  const size_t e1 = (size_t)min(row0 + 16 + rlo, n-1) * K + khi*8;

  AFrag<AT> c0,c1,x0f,x1f;
  c0.load(A + e0); c1.load(A + e1);

  #pragma unroll 1
  for(int k0=0; k0<K; k0+=32){
    if(k0+32 < K){
      x0f.load(A + e0 + k0 + 32);
      x1f.load(A + e1 + k0 + 32);
    }
    __syncthreads();     // previous tile fully consumed
    // stage B tile (hi+lo): global row f, 16B chunk kk8 -> granule (f>>4)*64 + kk8*16 + (f&15)
    #pragma unroll
    for(int j=0;j<F/64;j++){
      int i  = threadIdx.x + j*256;
      int f  = i >> 2;
      int k8 = i & 3;
      int g  = ((f>>4)<<6) + (k8<<4) + (f&15);
      size_t goff = (size_t)f*K + k0 + (k8<<3);
      sBh[g] = *(const uint4*)(Bh + goff);
      sBl[g] = *(const uint4*)(Bl + goff);
    }
    // convert current A fragments while staging loads are in flight
    float scr[8], shr[8];
    if(BN){
      float4 s0 = *(const float4*)(sc + k0 + khi*8);
      float4 s1 = *(const float4*)(sc + k0 + khi*8 + 4);
      float4 t0 = *(const float4*)(sh + k0 + khi*8);
      float4 t1 = *(const float4*)(sh + k0 + khi*8 + 4);
      scr[0]=s0.x;scr[1]=s0.y;scr[2]=s0.z;scr[3]=s0.w;scr[4]=s1.x;scr[5]=s1.y;scr[6]=s1.z;scr[7]=s1.w;
      shr[0]=t0.x;shr[1]=t0.y;shr[2]=t0.z;shr[3]=t0.w;shr[4]=t1.x;shr[5]=t1.y;shr[6]=t1.z;shr[7]=t1.w;
    }
    union { unsigned short u[8]; bf16x8 v; } H0,L0,H1,L1;
    {
      float v0[8], v1[8];
      c0.get(v0); c1.get(v1);
      #pragma unroll
      for(int j=0;j<8;j++){
        float y0 = v0[j], y1 = v1[j];
        if(BN){ y0 = fmaxf(fmaf(y0,scr[j],shr[j]),0.f); y1 = fmaxf(fmaf(y1,scr[j],shr[j]),0.f); }
        unsigned short h0 = f2bf(y0), h1 = f2bf(y1);
        H0.u[j]=h0; L0.u[j]=f2bf(y0 - bfhi(h0));
        H1.u[j]=h1; L1.u[j]=f2bf(y1 - bfhi(h1));
      }
    }
    bf16x8 ah0=H0.v, al0=L0.v, ah1=H1.v, al1=L1.v;
    __syncthreads();     // staging complete
    #pragma unroll
    for(int cf=0; cf<NF; cf++){
      bf16x8 bh = ((const bf16x8*)sBh)[cf*64 + l];   // stride-1 b128: conflict-free
      bf16x8 bl = ((const bf16x8*)sBl)[cf*64 + l];
      acc[0][cf] = __builtin_amdgcn_mfma_f32_16x16x32_bf16(ah0, bh, acc[0][cf], 0,0,0);
      acc[1][cf] = __builtin_amdgcn_mfma_f32_16x16x32_bf16(ah1, bh, acc[1][cf], 0,0,0);
      acc[0][cf] = __builtin_amdgcn_mfma_f32_16x16x32_bf16(al0, bh, acc[0][cf], 0,0,0);
      acc[1][cf] = __builtin_amdgcn_mfma_f32_16x16x32_bf16(al1, bh, acc[1][cf], 0,0,0);
      acc[0][cf] = __builtin_amdgcn_mfma_f32_16x16x32_bf16(ah0, bl, acc[0][cf], 0,0,0);
      acc[1][cf] = __builtin_amdgcn_mfma_f32_16x16x32_bf16(ah1, bl, acc[1][cf], 0,0,0);
    }
    c0=x0f; c1=x1f;
  }

  // epilogue: C/D layout col=lane&15 (+16cf), row=(lane>>4)*4+reg (+16rf)
  #pragma unroll
  for(int rf=0; rf<2; rf++){
    #pragma unroll
    for(int r=0; r<4; r++){
      int m = row0 + rf*16 + khi*4 + r;
      if(m < n){
        float rs = RSC ? rsc[m] : 1.f;
        #pragma unroll
        for(int cf=0; cf<NF; cf++){
          int col = rlo + 16*cf;
          float v = acc[rf][cf][r];
          if(BIAS) v += bias[col];
          v *= rs;
          C[(size_t)m*F + col] = (OT)v;
        }
      }
    }
  }
}

// ---------------- BatchNorm stats: two-stage, atomic-free ----------------
// Stage 1: block writes per-column partial sums to partials[blk][2F] (coalesced).
__global__ __launch_bounds__(256) void k_bn_stats16(const _Float16* __restrict__ h,
                            float* __restrict__ partials, int n, int lgF){
  const int F   = 1 << lgF;
  const int C8  = 1 << (lgF-3);            // f16x8 chunks per row
  const int c8  = threadIdx.x & (C8-1);
  const int sub = threadIdx.x >> (lgF-3);
  const int rpb = 256 >> (lgF-3);          // rows per pass per block
  float s[8], s2[8];
  #pragma unroll
  for(int j=0;j<8;j++){ s[j]=0.f; s2[j]=0.f; }
  for(int row = blockIdx.x*rpb + sub; row < n; row += gridDim.x*rpb){
    f16x8 v = ((const f16x8*)h)[(size_t)row*C8 + c8];
    #pragma unroll
    for(int j=0;j<8;j++){ float f=(float)v[j]; s[j]+=f; s2[j]=fmaf(f,f,s2[j]); }
  }
  __shared__ float rs [256*9];
  __shared__ float rs2[256*9];
  #pragma unroll
  for(int j=0;j<8;j++){ rs[threadIdx.x*9+j]=s[j]; rs2[threadIdx.x*9+j]=s2[j]; }
  __syncthreads();
  for(int half = rpb>>1; half>=1; half>>=1){
    if(sub < half){
      int o = (threadIdx.x + half*C8)*9;
      #pragma unroll
      for(int j=0;j<8;j++){ rs[threadIdx.x*9+j]+=rs[o+j]; rs2[threadIdx.x*9+j]+=rs2[o+j]; }
    }
    __syncthreads();
  }
  if(sub==0){
    float* p = partials + (size_t)blockIdx.x*(2*F);
    #pragma unroll
    for(int j=0;j<8;j++){
      p[c8*8+j]     = rs [threadIdx.x*9+j];
      p[F + c8*8+j] = rs2[threadIdx.x*9+j];
    }
  }
}

// Stage 2: column c of stats = sum over BN_G1 partial rows. grid = 2F/64, block = 64.
__global__ void k_bn_colsum(const float* __restrict__ partials, float* __restrict__ out, int F2){
  int c = blockIdx.x*64 + threadIdx.x;
  float s = 0.f;
  #pragma unroll 8
  for(int b=0; b<BN_G1; b++) s += partials[(size_t)b*F2 + c];
  out[c] = s;
}

__global__ void k_bn_finalize(const float* __restrict__ sums, const float* __restrict__ sumsq,
                              const float* __restrict__ g, const float* __restrict__ be,
                              float* __restrict__ scale, float* __restrict__ shift, int n, int F){
  int f = threadIdx.x;
  if(f<F){
    float mu = sums[f]/(float)n;
    float var = sumsq[f]/(float)n - mu*mu;
    float sc = g[f]*rsqrtf(var+1e-5f);
    scale[f] = sc;
    shift[f] = fmaf(-mu, sc, be[f]);
  }
}

// ---------------- head: (BN2+relu) + LN + attention + pool + MLP ----------------

__global__ void k_ln_att(const _Float16* __restrict__ x, const float* __restrict__ bsc, const float* __restrict__ bsh,
                         const float* __restrict__ g, const float* __restrict__ b,
                         const float* __restrict__ att, float* __restrict__ lnx, float* __restrict__ wv,
                         float* __restrict__ Ssum, int n){
  int lane = threadIdx.x & 63;
  int wid = (blockIdx.x<<2) + (threadIdx.x>>6);
  float gl=g[lane], bl=b[lane], al=att[lane];
  float scl=bsc[lane], shl=bsh[lane];
  float wacc=0.f;
  for(int node=wid; node<n; node+=4096){
    float raw = (float)x[((size_t)node<<6)+lane];
    float v = fmaxf(fmaf(raw, scl, shl), 0.f);     // fused BN2 + relu
    float s=v;
    #pragma unroll
    for(int o=32;o>0;o>>=1) s += __shfl_xor(s,o);
    float mu = s*0.015625f;
    float d = v-mu;
    float q = d*d;
    #pragma unroll
    for(int o=32;o>0;o>>=1) q += __shfl_xor(q,o);
    float ln = d*rsqrtf(q*0.015625f + 1e-5f)*gl + bl;
    lnx[((size_t)node<<6)+lane] = ln;
    float a = ln*al;
    #pragma unroll
    for(int o=32;o>0;o>>=1) a += __shfl_xor(a,o);
    float wgt = expf(tanhf(a));
    if(lane==0) wv[node]=wgt;
    wacc += wgt;
  }
  __shared__ float sred[4];
  if(lane==0) sred[threadIdx.x>>6]=wacc;
  __syncthreads();
  if(threadIdx.x==0) atomicAdd(Ssum, sred[0]+sred[1]+sred[2]+sred[3]);
}

__global__ void k_pool(const float* __restrict__ lnx, const float* __restrict__ wv,
                       const int* __restrict__ batch, float* __restrict__ psum, int n){
  int lane = threadIdx.x & 63;
  int wave = threadIdx.x >> 6;
  int start = blockIdx.x*512 + wave*128;
  if(start >= n) return;
  int end = min(start+128, n);
  int cur = batch[start];
  float acc = 0.f;
  for(int i=start;i<end;i++){
    int bb = batch[i];
    if(bb != cur){ atomicAdd(&psum[cur*64+lane], acc); acc=0.f; cur=bb; }
    acc = fmaf(lnx[(size_t)i*64+lane], wv[i], acc);
  }
  atomicAdd(&psum[cur*64+lane], acc);
}

__global__ void k_mlp(const float* __restrict__ psum, const int* __restrict__ cnt,
                      const float* __restrict__ Ssum,
                      const float* __restrict__ M0W, const float* __restrict__ M0b,
                      const float* __restrict__ M1W, const float* __restrict__ M1b,
                      const float* __restrict__ M2W, const float* __restrict__ M2b,
                      float* __restrict__ out){
  int b = threadIdx.x;
  float S = Ssum[0];
  int cb = cnt[b]; if(cb<1) cb=1;
  float inv = 1.f/(S*(float)cb);
  float p[64];
  #pragma unroll
  for(int f=0;f<64;f++) p[f] = psum[b*64+f]*inv;
  float h1[32];
  #pragma unroll
  for(int j=0;j<32;j++){
    float a=M0b[j];
    #pragma unroll
    for(int f=0;f<64;f++) a = fmaf(p[f], M0W[f*32+j], a);
    h1[j]=fmaxf(a,0.f);
  }
  float h2[16];
  #pragma unroll
  for(int j=0;j<16;j++){
    float a=M1b[j];
    #pragma unroll
    for(int f=0;f<32;f++) a = fmaf(h1[f], M1W[f*16+j], a);
    h2[j]=fmaxf(a,0.f);
  }
  #pragma unroll
  for(int j=0;j<2;j++){
    float a=M2b[j];
    #pragma unroll
    for(int f=0;f<16;f++) a = fmaf(h2[f], M2W[f*2+j], a);
    out[b*2+j]=a;
  }
}

// ---------------- launch ----------------

extern "C" void kernel_launch(void* const* d_in, const int* in_sizes, int n_in,
                              void* d_out, int out_size, void* d_ws, size_t ws_size,
                              hipStream_t stream){
  const float* x   = (const float*)d_in[0];
  const int*   ei  = (const int*)d_in[1];
  const int* batch = (const int*)d_in[2];
  const float* W0=(const float*)d_in[3],  *b0=(const float*)d_in[4],  *g0=(const float*)d_in[5],  *be0=(const float*)d_in[6];
  const float* W1=(const float*)d_in[7],  *b1=(const float*)d_in[8],  *g1=(const float*)d_in[9],  *be1=(const float*)d_in[10];
  const float* W2=(const float*)d_in[11], *b2=(const float*)d_in[12], *g2=(const float*)d_in[13], *be2=(const float*)d_in[14];
  const float* ln_g=(const float*)d_in[15], *ln_b=(const float*)d_in[16], *att=(const float*)d_in[17];
  const float* M0W=(const float*)d_in[18], *M0b=(const float*)d_in[19];
  const float* M1W=(const float*)d_in[20], *M1b=(const float*)d_in[21];
  const float* M2W=(const float*)d_in[22], *M2b=(const float*)d_in[23];
  const int N = in_sizes[0]/128;
  const int E = in_sizes[1]/2;
  const int* srcv = ei;
  const int* dstv = ei + E;
  // magic for range-id = floor(d*8/N): M = ceil(8*2^40/N); exact for d < 2^17
  const unsigned long long Mdiv = ((8ULL<<40) + (unsigned long long)N - 1) / (unsigned long long)N;

  char* base = (char*)d_ws;
  size_t off = 0;
  auto alloc = [&](size_t bytes)->char*{ char* p = base+off; off = (off+bytes+255)&~(size_t)255; return p; };
  // zeroed region first
  int*   deg    = (int*)  alloc((size_t)N*4);
  int*   cnt    = (int*)  alloc(64*4);
  float* psum   = (float*)alloc(64*64*4);
  float* Ssum   = (float*)alloc(4);
  size_t zero_bytes = off;
  float* stats  = (float*)alloc(6*256*4);
  float* dinv   = (float*)alloc((size_t)N*4);
  int*   rowptr = (int*)  alloc(((size_t)N+1)*4);
  int*   cursor = (int*)  alloc((size_t)N*4);
  int*   bsum   = (int*)  alloc(128*4);
  float* bnsc   = (float*)alloc(3*256*4);
  float* bnsh   = (float*)alloc(3*256*4);
  float* partials = (float*)alloc((size_t)BN_G1*512*4);   // [G1][2F], F<=256
  unsigned short* Wh0 = (unsigned short*)alloc((size_t)128*256*2);
  unsigned short* Wl0 = (unsigned short*)alloc((size_t)128*256*2);
  unsigned short* Wh1 = (unsigned short*)alloc((size_t)256*128*2);
  unsigned short* Wl1 = (unsigned short*)alloc((size_t)256*128*2);
  unsigned short* Wh2 = (unsigned short*)alloc((size_t)128*64*2);
  unsigned short* Wl2 = (unsigned short*)alloc((size_t)128*64*2);
  int*   adj    = (int*)  alloc((size_t)E*4);
  _Float16* x16 = (_Float16*)alloc((size_t)N*128*2);
  _Float16* R16 = (_Float16*)alloc((size_t)N*128*2);   // agg outputs (layers 0,1)
  _Float16* P16 = (_Float16*)alloc((size_t)N*256*2);   // layer-0 pre-BN h
  _Float16* Q16 = (_Float16*)alloc((size_t)N*128*2);   // GEMM1/2 outputs
  _Float16* O16 = (_Float16*)alloc((size_t)N*64*2);    // layer-2 pre-BN h
  float* LNX    = (float*)alloc((size_t)N*64*4);
  float* WV     = (float*)alloc((size_t)N*4);
  (void)ws_size; (void)n_in; (void)out_size;

  hipMemsetAsync(d_ws, 0, zero_bytes, stream);

  // graph structure + weight prep
  k_deg_hist  <<<2048,256,0,stream>>>(dstv, deg, E, Mdiv);
  k_batch_hist<<<256,256,0,stream>>>(batch, cnt, N);
  k_dinv      <<<(N+255)/256,256,0,stream>>>(deg, dinv, N);
  int nblk = (N+1023)/1024;
  k_scan1<<<nblk,256,0,stream>>>(deg, bsum, N);
  k_scan2<<<1,128,0,stream>>>(bsum, nblk, rowptr, N);
  k_scan3<<<nblk,256,0,stream>>>(deg, bsum, rowptr, cursor, N);
  k_csr_fill<<<2048,256,0,stream>>>(srcv, dstv, cursor, adj, E, Mdiv);
  k_prep_w<<<(128*256+255)/256,256,0,stream>>>(W0, Wh0, Wl0, 128, 256);
  k_prep_w<<<(256*128+255)/256,256,0,stream>>>(W1, Wh1, Wl1, 256, 128);
  k_prep_w<<<(128*64 +255)/256,256,0,stream>>>(W2, Wh2, Wl2, 128, 64);
  k_prep_x<<<(N*32+255)/256,256,0,stream>>>(x, dinv, x16, N);

  const int gemm_grid = (N+127)/128;

  // ---- layer 0: R16 = agg(x*dinv); P16 = R16@W0 + b0; stats ----
  k_agg16<<<(N*16+255)/256,256,0,stream>>>(x16, rowptr, adj, dinv, nullptr, R16, N, 4);
  k_gemm_mfma<128,256,false,true,false,_Float16,_Float16><<<gemm_grid,256,0,stream>>>(R16, Wh0, Wl0, nullptr,nullptr, b0, nullptr, P16, N);
  k_bn_stats16<<<BN_G1,256,0,stream>>>(P16, partials, N, 8);
  k_bn_colsum<<<512/64,64,0,stream>>>(partials, stats+0, 512);
  k_bn_finalize<<<1,256,0,stream>>>(stats+0, stats+256, g0, be0, bnsc+0, bnsh+0, N, 256);

  // ---- layer 1: Q16 = relu(bn0(P16))@W1 * dinv; R16 = agg(Q16) + b1; stats ----
  k_gemm_mfma<256,128,true,false,true,_Float16,_Float16><<<gemm_grid,256,0,stream>>>(P16, Wh1, Wl1, bnsc+0, bnsh+0, nullptr, dinv, Q16, N);
  k_agg16<<<(N*16+255)/256,256,0,stream>>>(Q16, rowptr, adj, dinv, b1, R16, N, 4);
  k_bn_stats16<<<BN_G1,256,0,stream>>>(R16, partials, N, 7);
  k_bn_colsum<<<256/64,64,0,stream>>>(partials, stats+512, 256);
  k_bn_finalize<<<1,256,0,stream>>>(stats+512, stats+640, g1, be1, bnsc+256, bnsh+256, N, 128);

  // ---- layer 2: Q16 = relu(bn1(R16))@W2 * dinv; O16 = agg(Q16) + b2; stats ----
  k_gemm_mfma<128,64,true,false,true,_Float16,_Float16><<<gemm_grid,256,0,stream>>>(R16, Wh2, Wl2, bnsc+256, bnsh+256, nullptr, dinv, Q16, N);
  k_agg16<<<(N*8+255)/256,256,0,stream>>>(Q16, rowptr, adj, dinv, b2, O16, N, 3);
  k_bn_stats16<<<BN_G1,256,0,stream>>>(O16, partials, N, 6);
  k_bn_colsum<<<128/64,64,0,stream>>>(partials, stats+1024, 128);
  k_bn_finalize<<<1,256,0,stream>>>(stats+1024, stats+1088, g2, be2, bnsc+512, bnsh+512, N, 64);

  // ---- head (BN2+relu fused into ln_att) ----
  k_ln_att<<<1024,256,0,stream>>>(O16, bnsc+512, bnsh+512, ln_g, ln_b, att, LNX, WV, Ssum, N);
  k_pool  <<<(N+511)/512,256,0,stream>>>(LNX, WV, batch, psum, N);
  k_mlp   <<<1,64,0,stream>>>(psum, cnt, Ssum, M0W,M0b,M1W,M1b,M2W,M2b, (float*)d_out);
}